// Round 4
// baseline (255.125 us; speedup 1.0000x reference)
//
#include <hip/hip_runtime.h>
#include <hip/hip_bf16.h>

using bf16 = __hip_bfloat16;

constexpr int N_ = 2048;    // nodes
constexpr int E_ = 4096;    // edges
constexpr int CAP = 64;     // max nnz per adjacency row

__device__ __forceinline__ void unpack8(uint4 u, float* f) {
    unsigned w0 = u.x, w1 = u.y, w2 = u.z, w3 = u.w;
    f[0] = __uint_as_float(w0 << 16); f[1] = __uint_as_float(w0 & 0xffff0000u);
    f[2] = __uint_as_float(w1 << 16); f[3] = __uint_as_float(w1 & 0xffff0000u);
    f[4] = __uint_as_float(w2 << 16); f[5] = __uint_as_float(w2 & 0xffff0000u);
    f[6] = __uint_as_float(w3 << 16); f[7] = __uint_as_float(w3 & 0xffff0000u);
}

__device__ __forceinline__ void load8(const void* p, long long base, int isbf, float* f) {
    if (isbf) {
        uint4 u = *(const uint4*)((const unsigned short*)p + base);
        unpack8(u, f);
    } else {
        const float4* q = (const float4*)((const float*)p + base);
        float4 a = q[0], b = q[1];
        f[0] = a.x; f[1] = a.y; f[2] = a.z; f[3] = a.w;
        f[4] = b.x; f[5] = b.y; f[6] = b.z; f[7] = b.w;
    }
}

// ---- dtype detect: T holds {0,1,2}; f32 stream -> low16 of every u32 is 0
__global__ void k_detect(const unsigned int* __restrict__ t32, int* __restrict__ flag) {
    long long i = (long long)(blockIdx.x * blockDim.x + threadIdx.x) * 4;
    uint4 u = *(const uint4*)(t32 + i);
    if ((u.x | u.y | u.z | u.w) & 0xFFFFu) *flag = 1;
}

constexpr int NCONV = 23;
constexpr int CHUNK = 8192;
struct ConvArgs {
    const void* src[NCONV];
    float* dst[NCONV];
    int n[NCONV];
    int first[NCONV];
    unsigned char blk_entry[64];
};

struct GArgs {
    const void* T; const void* adjV; const void* adjE;
    int* dt;
    int* tcnt; int* trows; float* tvals;
    int* avc; int* avj; float* avv;
    int* aec; int* aej; float* aev;
    int* eav; float* eprod;
    float *d1, *d2, *d3;            // avco deltas (zeroed by memset)
    float *aea1, *aea2, *colmax1, *colmax2;
    float *s_n1, *s_n2;
    float *Xf, *Zf;
    float *W1f, *p1f, *b1f, *Wf1f, *g1f, *be1f;
    float *W2f, *p2f, *b2f, *Wf2f, *g2f, *be2f;
    float *W3f, *p3f, *b3f, *W4f, *p4f, *b4f;
    float *W5f, *p5f, *b5f;
    float *X1F1, *F2, *HW, *HeW, *HeW2, *X3;
    void* out;
};

// ---- rare-path emitter (INLINE — a noinline call forces an ABI frame and
// scratch spills: +216 MB HBM traffic measured. Keep inline.)
__device__ __forceinline__ void emit_one(const GArgs& a, int region,
                                         long long idx, float v) {
    if (region == 0) {              // T: N x E
        int e = (int)(idx & (E_ - 1));
        int n = (int)(idx >> 12);
        int p = atomicAdd(&a.tcnt[e], 1);
        if (p < 2) { a.trows[e * 2 + p] = n; a.tvals[e * 2 + p] = v; }
    } else if (region == 1) {       // adjV: N x N
        int row = (int)(idx >> 11), col = (int)(idx & (N_ - 1));
        int s = atomicAdd(&a.avc[row], 1);
        if (s < CAP) { a.avj[row * CAP + s] = col; a.avv[row * CAP + s] = v; }
    } else {                        // adjE: E x E
        int row = (int)(idx >> 12), col = (int)(idx & (E_ - 1));
        int s = atomicAdd(&a.aec[row], 1);
        if (s < CAP) { a.aej[row * CAP + s] = col; a.aev[row * CAP + s] = v; }
    }
}

__device__ __forceinline__ void emit_bf2(const GArgs& a, int region,
                                         long long e0, unsigned w) {
    if (w & 0xFFFFu) emit_one(a, region, e0,     __uint_as_float(w << 16));
    if (w >> 16)     emit_one(a, region, e0 + 1, __uint_as_float(w & 0xffff0000u));
}

// ---- fused extraction + upconvert
// bf16 scan: per-wave 8 KB chunk staged to LDS via global_load_lds DMA
// (structural MLP=8, zero VGPR held across the loads — the register version
// was serialized to MLP~2 by the allocator at 28 VGPRs, 49 us / 1.5 TB/s).
// Then ds_read_b128 readback with bit-level OR early-out; rare emits re-read LDS.
__global__ void __launch_bounds__(256) k_extract_all(GArgs a, ConvArgs ca) {
    __shared__ uint4 smem4[2048];   // 32 KB: 4 waves x 8 KB
    int b = blockIdx.x, t = threadIdx.x;
    int isbf = a.dt[1];
    if (b < 1792) {                 // sparse extraction of T / adjV / adjE
        int region; const void* src; long long elem0;
        if (b < 512)      { region = 0; src = a.T;    elem0 = (long long)b << 14; }
        else if (b < 768) { region = 1; src = a.adjV; elem0 = (long long)(b - 512) << 14; }
        else              { region = 2; src = a.adjE; elem0 = (long long)(b - 768) << 14; }
        int ln = t & 63, w = t >> 6;
        long long wbase = elem0 + (long long)w * 4096;   // 4096 elems per wave
        if (isbf) {
            const unsigned char* g = (const unsigned char*)src + wbase * 2;
            char* lb = (char*)(smem4 + (size_t)w * 512);
#pragma unroll
            for (int j = 0; j < 8; j++) {
                __builtin_amdgcn_global_load_lds(
                    (const __attribute__((address_space(1))) void*)(g + j * 1024 + (size_t)ln * 16),
                    (__attribute__((address_space(3))) void*)(lb + j * 1024),
                    16, 0, 0);
            }
            asm volatile("s_waitcnt vmcnt(0)" ::: "memory");
            const uint4* l4 = (const uint4*)lb;
            unsigned any = 0;
#pragma unroll
            for (int j = 0; j < 8; j++) {
                uint4 u = l4[j * 64 + ln];
                any |= u.x | u.y | u.z | u.w;
            }
            if (any) {
#pragma unroll
                for (int j = 0; j < 8; j++) {
                    uint4 u = l4[j * 64 + ln];
                    long long eb = wbase + (long long)(j * 64 + ln) * 8;
                    if (u.x) emit_bf2(a, region, eb,     u.x);
                    if (u.y) emit_bf2(a, region, eb + 2, u.y);
                    if (u.z) emit_bf2(a, region, eb + 4, u.z);
                    if (u.w) emit_bf2(a, region, eb + 6, u.w);
                }
            }
        } else {                    // f32 fallback (correctness path)
            const uint4* q = (const uint4*)((const float*)src + wbase);
#pragma unroll
            for (int h = 0; h < 2; h++) {
                uint4 u[8];
#pragma unroll
                for (int j = 0; j < 8; j++) u[j] = q[h * 512 + j * 64 + ln];
                unsigned any = 0;
#pragma unroll
                for (int j = 0; j < 8; j++) any |= u[j].x | u[j].y | u[j].z | u[j].w;
                if (any) {
#pragma unroll
                    for (int j = 0; j < 8; j++) {
                        long long eb = wbase + (long long)(h * 512 + j * 64 + ln) * 4;
                        if (u[j].x) emit_one(a, region, eb,     __uint_as_float(u[j].x));
                        if (u[j].y) emit_one(a, region, eb + 1, __uint_as_float(u[j].y));
                        if (u[j].z) emit_one(a, region, eb + 2, __uint_as_float(u[j].z));
                        if (u[j].w) emit_one(a, region, eb + 3, __uint_as_float(u[j].w));
                    }
                }
            }
        }
    } else {                        // upconvert inputs to f32
        int gb = b - 1792;
        int e = ca.blk_entry[gb];
        int off = (gb - ca.first[e]) * CHUNK;
        int n = ca.n[e];
        const void* src = ca.src[e];
        float* dst = ca.dst[e];
        int lim = min(off + CHUNK, n);
        for (int i = off + t * 8; i < lim; i += 256 * 8) {
            float f[8]; load8(src, i, isbf, f);
            float4* d = (float4*)(dst + i);
            d[0] = make_float4(f[0], f[1], f[2], f[3]);
            d[1] = make_float4(f[4], f[5], f[6], f[7]);
        }
    }
}

// ---- stage A: edge_map+gate1+scatter1 | edge_feat | fused W1 & Wf1 gemm+LN (4 rows/block)
__global__ void __launch_bounds__(128) k_stageA(GArgs a) {
    __shared__ float lds[256];
    __shared__ float red[8];
    int b = blockIdx.x, t = threadIdx.x;
    if (b < 32) {                   // per-edge: map + gate p1 + scatter into d1
        int e = b * 128 + t;
        if (a.tcnt[e] < 2) { a.eav[2 * e] = -1; a.eav[2 * e + 1] = -1; a.eprod[e] = 0.f; return; }
        int p = a.trows[2 * e], q = a.trows[2 * e + 1];
        int ia = -1, ib = -1;
        int np = min(a.avc[p], CAP), nq = min(a.avc[q], CAP);
        for (int s = 0; s < np; s++) if (a.avj[p * CAP + s] == q) { ia = p * CAP + s; break; }
        for (int s = 0; s < nq; s++) if (a.avj[q * CAP + s] == p) { ib = q * CAP + s; break; }
        float ep = a.tvals[2 * e] * a.tvals[2 * e + 1];
        a.eav[2 * e] = ia; a.eav[2 * e + 1] = ib; a.eprod[e] = ep;
        const float4* zr = (const float4*)(a.Zf + (long long)e * 16);
        const float4* pr = (const float4*)a.p1f;
        float s = 0.f;
#pragma unroll
        for (int qq = 0; qq < 4; qq++) {
            float4 h = zr[qq], pp = pr[qq];
            s += h.x * pp.x + h.y * pp.y + h.z * pp.z + h.w * pp.w;
        }
        float c = ep * s;
        if (ia >= 0) unsafeAtomicAdd(&a.d1[ia], a.avv[ia] * c);
        if (ib >= 0) unsafeAtomicAdd(&a.d1[ib], a.avv[ib] * c);
    } else if (b < 64) {            // edge_feat: HeW = relu(Z)@W2 ; F2 = relu(LN(Z@Wf2))
        int e = (b - 32) * 128 + t;
        const float4* zr = (const float4*)(a.Zf + (long long)e * 16);
        float zv[16];
        float4 z0 = zr[0], z1 = zr[1], z2 = zr[2], z3 = zr[3];
        zv[0] = z0.x; zv[1] = z0.y; zv[2] = z0.z; zv[3] = z0.w;
        zv[4] = z1.x; zv[5] = z1.y; zv[6] = z1.z; zv[7] = z1.w;
        zv[8] = z2.x; zv[9] = z2.y; zv[10] = z2.z; zv[11] = z2.w;
        zv[12] = z3.x; zv[13] = z3.y; zv[14] = z3.z; zv[15] = z3.w;
        float hw[16], f2[16];
#pragma unroll
        for (int c = 0; c < 16; c++) { hw[c] = 0.f; f2[c] = 0.f; }
#pragma unroll
        for (int k = 0; k < 16; k++) {
            float ar = fmaxf(zv[k], 0.f), az = zv[k];
#pragma unroll
            for (int c = 0; c < 16; c++) {
                hw[c] += ar * a.W2f[k * 16 + c];
                f2[c] += az * a.Wf2f[k * 16 + c];
            }
        }
        float m = 0.f;
#pragma unroll
        for (int c = 0; c < 16; c++) m += f2[c];
        m *= (1.f / 16.f);
        float var = 0.f;
#pragma unroll
        for (int c = 0; c < 16; c++) { float d = f2[c] - m; var += d * d; }
        var *= (1.f / 16.f);
        float rs = rsqrtf(var + 1e-5f);
#pragma unroll
        for (int c = 0; c < 16; c++)
            f2[c] = fmaxf((f2[c] - m) * rs * a.g2f[c] + a.be2f[c], 0.f);
        float4* ho = (float4*)(a.HeW + (long long)e * 16);
        ho[0] = make_float4(hw[0], hw[1], hw[2], hw[3]);
        ho[1] = make_float4(hw[4], hw[5], hw[6], hw[7]);
        ho[2] = make_float4(hw[8], hw[9], hw[10], hw[11]);
        ho[3] = make_float4(hw[12], hw[13], hw[14], hw[15]);
        float4* fo = (float4*)(a.F2 + (long long)e * 16);
        fo[0] = make_float4(f2[0], f2[1], f2[2], f2[3]);
        fo[1] = make_float4(f2[4], f2[5], f2[6], f2[7]);
        fo[2] = make_float4(f2[8], f2[9], f2[10], f2[11]);
        fo[3] = make_float4(f2[12], f2[13], f2[14], f2[15]);
    } else {                        // fused gemm W1 + gemmln Wf1, 4 rows/block
        int r0 = (b - 64) * 4;
        for (int j = t; j < 256; j += 128) lds[j] = a.Xf[(long long)r0 * 64 + j];
        __syncthreads();
        float h0 = 0.f, h1 = 0.f, h2 = 0.f, h3 = 0.f;
        float f0 = 0.f, f1 = 0.f, f2 = 0.f, f3 = 0.f;
#pragma unroll 8
        for (int k = 0; k < 64; k++) {
            float w1 = a.W1f[k * 128 + t], wf = a.Wf1f[k * 128 + t];
            float x0 = lds[k], x1 = lds[64 + k], x2 = lds[128 + k], x3 = lds[192 + k];
            h0 += x0 * w1; h1 += x1 * w1; h2 += x2 * w1; h3 += x3 * w1;
            f0 += x0 * wf; f1 += x1 * wf; f2 += x2 * wf; f3 += x3 * wf;
        }
        a.HW[(long long)(r0 + 0) * 128 + t] = h0;
        a.HW[(long long)(r0 + 1) * 128 + t] = h1;
        a.HW[(long long)(r0 + 2) * 128 + t] = h2;
        a.HW[(long long)(r0 + 3) * 128 + t] = h3;
        // LayerNorm over 128 cols for the 4 rows (Wf1 path)
        float s0 = f0, s1 = f1, s2 = f2, s3 = f3;
        for (int o = 32; o > 0; o >>= 1) {
            s0 += __shfl_down(s0, o); s1 += __shfl_down(s1, o);
            s2 += __shfl_down(s2, o); s3 += __shfl_down(s3, o);
        }
        if ((t & 63) == 0) {
            int w4 = (t >> 6) * 4;
            red[w4] = s0; red[w4 + 1] = s1; red[w4 + 2] = s2; red[w4 + 3] = s3;
        }
        __syncthreads();
        float m0 = (red[0] + red[4]) * (1.f / 128.f);
        float m1 = (red[1] + red[5]) * (1.f / 128.f);
        float m2 = (red[2] + red[6]) * (1.f / 128.f);
        float m3 = (red[3] + red[7]) * (1.f / 128.f);
        __syncthreads();
        float d0 = f0 - m0, d1 = f1 - m1, d2 = f2 - m2, d3 = f3 - m3;
        s0 = d0 * d0; s1 = d1 * d1; s2 = d2 * d2; s3 = d3 * d3;
        for (int o = 32; o > 0; o >>= 1) {
            s0 += __shfl_down(s0, o); s1 += __shfl_down(s1, o);
            s2 += __shfl_down(s2, o); s3 += __shfl_down(s3, o);
        }
        if ((t & 63) == 0) {
            int w4 = (t >> 6) * 4;
            red[w4] = s0; red[w4 + 1] = s1; red[w4 + 2] = s2; red[w4 + 3] = s3;
        }
        __syncthreads();
        float v0 = (red[0] + red[4]) * (1.f / 128.f);
        float v1 = (red[1] + red[5]) * (1.f / 128.f);
        float v2 = (red[2] + red[6]) * (1.f / 128.f);
        float v3 = (red[3] + red[7]) * (1.f / 128.f);
        float g = a.g1f[t], be = a.be1f[t];
        a.X1F1[(long long)(r0 + 0) * 256 + 128 + t] = fmaxf(d0 * rsqrtf(v0 + 1e-5f) * g + be, 0.f);
        a.X1F1[(long long)(r0 + 1) * 256 + 128 + t] = fmaxf(d1 * rsqrtf(v1 + 1e-5f) * g + be, 0.f);
        a.X1F1[(long long)(r0 + 2) * 256 + 128 + t] = fmaxf(d2 * rsqrtf(v2 + 1e-5f) * g + be, 0.f);
        a.X1F1[(long long)(r0 + 3) * 256 + 128 + t] = fmaxf(d3 * rsqrtf(v3 + 1e-5f) * g + be, 0.f);
    }
}

// ---- apply_node1 (delta form) + fused gate p2 -> s_n1
__global__ void __launch_bounds__(128) k_node1(GArgs a) {
    __shared__ float sm[2];
    int i = blockIdx.x, c = threadIdx.x;
    float acc = a.b1f[c];
    int n = min(a.avc[i], CAP);
    for (int s = 0; s < n; s++) {
        int idx = i * CAP + s;
        int col = a.avj[idx];
        float co = (col == i) ? a.avv[idx] : a.d1[idx];
        acc += co * a.HW[(long long)col * 128 + c];
    }
    acc = fmaxf(acc, 0.f);
    a.X1F1[(long long)i * 256 + c] = acc;
    float f = a.X1F1[(long long)i * 256 + 128 + c];
    float v = acc * a.p2f[c] + f * a.p2f[128 + c];
    for (int o = 32; o > 0; o >>= 1) v += __shfl_down(v, o);
    if ((c & 63) == 0) sm[c >> 6] = v;
    __syncthreads();
    if (c == 0) a.s_n1[i] = sm[0] + sm[1];
}

__device__ __forceinline__ void adjA_slot(const GArgs& a, int k, const float* sn,
                                          float* aea, float* colmax) {
    int e = k >> 6, s = k & 63;
    if (s >= min(a.aec[e], CAP)) return;
    int f = a.aej[k];
    float M;
    if (e == f) {
        M = 1.f;
    } else {
        M = 0.f;
        int ce = min(a.tcnt[e], 2), cf = min(a.tcnt[f], 2);
        for (int x = 0; x < ce; x++) {
            int nx = a.trows[2 * e + x]; float ux = a.tvals[2 * e + x];
            for (int y = 0; y < cf; y++)
                if (a.trows[2 * f + y] == nx) M += ux * a.tvals[2 * f + y] * sn[nx];
        }
    }
    float v = M * a.aev[k];
    aea[k] = v;
    if (v > 0.f) atomicMax((int*)&colmax[f], __float_as_int(v));
}

// ---- stage C: adjA1 | gemm W3 (K=256, 4 rows/block for weight reuse)
__global__ void __launch_bounds__(128) k_stageC(GArgs a) {
    __shared__ float lds[1024];
    int b = blockIdx.x, t = threadIdx.x;
    if (b < 2048) {
        adjA_slot(a, b * 128 + t, a.s_n1, a.aea1, a.colmax1);
    } else {
        int r0 = (b - 2048) * 4;
        for (int j = t; j < 1024; j += 128) lds[j] = a.X1F1[(long long)r0 * 256 + j];
        __syncthreads();
        float a0 = 0.f, a1 = 0.f, a2 = 0.f, a3 = 0.f;
        for (int k = 0; k < 256; k++) {
            float w = a.W3f[k * 128 + t];
            a0 += lds[k] * w; a1 += lds[256 + k] * w;
            a2 += lds[512 + k] * w; a3 += lds[768 + k] * w;
        }
        a.HW[(long long)r0 * 128 + t] = a0;
        a.HW[(long long)(r0 + 1) * 128 + t] = a1;
        a.HW[(long long)(r0 + 2) * 128 + t] = a2;
        a.HW[(long long)(r0 + 3) * 128 + t] = a3;
    }
}

// ---- edge layer 1: wave-per-edge SpMM + gate p3 + scatter d2 + fused W4 rowmat -> HeW2
__global__ void __launch_bounds__(256) k_edge1(GArgs a) {
    int e = (blockIdx.x * 256 + threadIdx.x) >> 6;
    int ln = threadIdx.x & 63;
    int sub = ln >> 4, c = ln & 15;
    float acc = 0.f;
    int n = min(a.aec[e], CAP);
    for (int s = sub; s < n; s += 4) {
        int idx = e * CAP + s;
        int f = a.aej[idx];
        float cm = a.colmax1[f];
        float nv = (cm != 0.f) ? a.aea1[idx] / cm : 0.f;
        acc += nv * a.HeW[(long long)f * 16 + c];
    }
    acc += __shfl_xor(acc, 16);
    acc += __shfl_xor(acc, 32);
    float tot = fmaxf(a.b2f[c] + acc, 0.f);         // Z2[e,c]
    float f2 = a.F2[(long long)e * 16 + c];
    // gate p3 over [Z2|F2]
    float v = tot * a.p3f[c] + f2 * a.p3f[16 + c];
#pragma unroll
    for (int m = 1; m < 16; m <<= 1) v += __shfl_xor(v, m);
    if (ln == 0) {
        float ep = a.eprod[e];
        if (ep != 0.f) {
            float cc = ep * v;
            int i1 = a.eav[2 * e], i2 = a.eav[2 * e + 1];
            if (i1 >= 0) unsafeAtomicAdd(&a.d2[i1], a.avv[i1] * cc);
            if (i2 >= 0) unsafeAtomicAdd(&a.d2[i2], a.avv[i2] * cc);
        }
    }
    // fused rowmat: HeW2[e,:] = [Z2|F2] @ W4  (in-register via shfl)
    float o = 0.f;
#pragma unroll
    for (int k = 0; k < 16; k++) {
        o += __shfl(tot, k, 16) * a.W4f[k * 16 + c];
        o += __shfl(f2, k, 16) * a.W4f[(16 + k) * 16 + c];
    }
    if (ln < 16) a.HeW2[(long long)e * 16 + c] = o;
}

// ---- apply_node3 + fused gate p4 -> s_n2
__global__ void __launch_bounds__(128) k_node3(GArgs a) {
    __shared__ float sm[2];
    int i = blockIdx.x, c = threadIdx.x;
    float acc = a.b3f[c];
    int n = min(a.avc[i], CAP);
    for (int s = 0; s < n; s++) {
        int idx = i * CAP + s;
        int col = a.avj[idx];
        float co = (col == i) ? a.avv[idx] : a.d2[idx];
        acc += co * a.HW[(long long)col * 128 + c];
    }
    acc = fmaxf(acc, 0.f);
    a.X3[(long long)i * 128 + c] = acc;
    float v = acc * a.p4f[c];
    for (int o = 32; o > 0; o >>= 1) v += __shfl_down(v, o);
    if ((c & 63) == 0) sm[c >> 6] = v;
    __syncthreads();
    if (c == 0) a.s_n2[i] = sm[0] + sm[1];
}

// ---- stage F: adjA2 | gemm W5 (K=128, 4 rows/block)
__global__ void __launch_bounds__(128) k_stageF(GArgs a) {
    __shared__ float lds[512];
    int b = blockIdx.x, t = threadIdx.x;
    if (b < 2048) {
        adjA_slot(a, b * 128 + t, a.s_n2, a.aea2, a.colmax2);
    } else {
        int r0 = (b - 2048) * 4;
        for (int j = t; j < 512; j += 128) lds[j] = a.X3[(long long)r0 * 128 + j];
        __syncthreads();
        float a0 = 0.f, a1 = 0.f, a2 = 0.f, a3 = 0.f;
        for (int k = 0; k < 128; k++) {
            float w = a.W5f[k * 128 + t];
            a0 += lds[k] * w; a1 += lds[128 + k] * w;
            a2 += lds[256 + k] * w; a3 += lds[384 + k] * w;
        }
        a.HW[(long long)r0 * 128 + t] = a0;
        a.HW[(long long)(r0 + 1) * 128 + t] = a1;
        a.HW[(long long)(r0 + 2) * 128 + t] = a2;
        a.HW[(long long)(r0 + 3) * 128 + t] = a3;
    }
}

// ---- edge layer 2: wave-per-edge SpMM + gate p5 + scatter d3 (Z4 never materialized)
__global__ void __launch_bounds__(256) k_edge2(GArgs a) {
    int e = (blockIdx.x * 256 + threadIdx.x) >> 6;
    int ln = threadIdx.x & 63;
    int sub = ln >> 4, c = ln & 15;
    float acc = 0.f;
    int n = min(a.aec[e], CAP);
    for (int s = sub; s < n; s += 4) {
        int idx = e * CAP + s;
        int f = a.aej[idx];
        float cm = a.colmax2[f];
        float nv = (cm != 0.f) ? a.aea2[idx] / cm : 0.f;
        acc += nv * a.HeW2[(long long)f * 16 + c];
    }
    acc += __shfl_xor(acc, 16);
    acc += __shfl_xor(acc, 32);
    float tot = fmaxf(a.b4f[c] + acc, 0.f);         // Z4[e,c]
    float v = tot * a.p5f[c];
#pragma unroll
    for (int m = 1; m < 16; m <<= 1) v += __shfl_xor(v, m);
    if (ln == 0) {
        float ep = a.eprod[e];
        if (ep != 0.f) {
            float cc = ep * v;
            int i1 = a.eav[2 * e], i2 = a.eav[2 * e + 1];
            if (i1 >= 0) unsafeAtomicAdd(&a.d3[i1], a.avv[i1] * cc);
            if (i2 >= 0) unsafeAtomicAdd(&a.d3[i2], a.avv[i2] * cc);
        }
    }
}

// ---- apply_node5 -> d_out
__global__ void __launch_bounds__(128) k_node5(GArgs a) {
    int i = blockIdx.x, c = threadIdx.x;
    float acc = a.b5f[c];
    int n = min(a.avc[i], CAP);
    for (int s = 0; s < n; s++) {
        int idx = i * CAP + s;
        int col = a.avj[idx];
        float co = (col == i) ? a.avv[idx] : a.d3[idx];
        acc += co * a.HW[(long long)col * 128 + c];
    }
    if (a.dt[1]) ((bf16*)a.out)[(long long)i * 128 + c] = __float2bfloat16(acc);
    else         ((float*)a.out)[(long long)i * 128 + c] = acc;
}

extern "C" void kernel_launch(void* const* d_in, const int* in_sizes, int n_in,
                              void* d_out, int out_size, void* d_ws, size_t ws_size,
                              hipStream_t stream) {
    char* wsB = (char*)d_ws;
    size_t off = 0;
    auto alloc = [&](size_t bytes) -> void* {
        void* p = wsB + off;
        off += (bytes + 255) & ~(size_t)255;
        return p;
    };
    // --- contiguous zero-init block (single memset ~1.65 MB) ---
    int*   dt      = (int*)alloc(2 * 4);
    int*   tcnt    = (int*)alloc(E_ * 4);
    int*   avc     = (int*)alloc(N_ * 4);
    int*   aec     = (int*)alloc(E_ * 4);
    float* colmax1 = (float*)alloc(E_ * 4);
    float* colmax2 = (float*)alloc(E_ * 4);
    float* d1      = (float*)alloc((size_t)N_ * CAP * 4);
    float* d2      = (float*)alloc((size_t)N_ * CAP * 4);
    float* d3      = (float*)alloc((size_t)N_ * CAP * 4);
    size_t zero_bytes = off;
    // --- converted f32 inputs ---
    float* Xf  = (float*)alloc((size_t)N_ * 64 * 4);
    float* Zf  = (float*)alloc((size_t)E_ * 16 * 4);
    float* W1f = (float*)alloc(8192 * 4);  float* p1f = (float*)alloc(16 * 4);
    float* b1f = (float*)alloc(128 * 4);
    float* Wf1f = (float*)alloc(8192 * 4); float* g1f = (float*)alloc(128 * 4);
    float* be1f = (float*)alloc(128 * 4);
    float* W2f = (float*)alloc(256 * 4);   float* p2f = (float*)alloc(256 * 4);
    float* b2f = (float*)alloc(16 * 4);
    float* Wf2f = (float*)alloc(256 * 4);  float* g2f = (float*)alloc(16 * 4);
    float* be2f = (float*)alloc(16 * 4);
    float* W3f = (float*)alloc(32768 * 4); float* p3f = (float*)alloc(32 * 4);
    float* b3f = (float*)alloc(128 * 4);
    float* W4f = (float*)alloc(512 * 4);   float* p4f = (float*)alloc(128 * 4);
    float* b4f = (float*)alloc(16 * 4);
    float* W5f = (float*)alloc(16384 * 4); float* p5f = (float*)alloc(16 * 4);
    float* b5f = (float*)alloc(128 * 4);
    // --- sparse structures + activations ---
    int*   trows  = (int*)alloc(E_ * 2 * 4);
    float* tvals  = (float*)alloc(E_ * 2 * 4);
    int*   avj    = (int*)alloc((size_t)N_ * CAP * 4);
    float* avv    = (float*)alloc((size_t)N_ * CAP * 4);
    int*   aej    = (int*)alloc((size_t)E_ * CAP * 4);
    float* aev    = (float*)alloc((size_t)E_ * CAP * 4);
    float* aea1   = (float*)alloc((size_t)E_ * CAP * 4);
    float* aea2   = (float*)alloc((size_t)E_ * CAP * 4);
    int*   eav    = (int*)alloc(E_ * 2 * 4);
    float* eprod  = (float*)alloc(E_ * 4);
    float* s_n1   = (float*)alloc(N_ * 4);
    float* s_n2   = (float*)alloc(N_ * 4);
    float* X1F1   = (float*)alloc((size_t)N_ * 256 * 4);
    float* F2b    = (float*)alloc((size_t)E_ * 16 * 4);
    float* HW     = (float*)alloc((size_t)N_ * 128 * 4);
    float* HeW    = (float*)alloc((size_t)E_ * 16 * 4);
    float* HeW2   = (float*)alloc((size_t)E_ * 16 * 4);
    float* X3     = (float*)alloc((size_t)N_ * 128 * 4);

    hipMemsetAsync(dt, 0, zero_bytes, stream);

    // 1) dtype detect (first 2 MB of T as u32)
    k_detect<<<512, 256, 0, stream>>>((const unsigned int*)d_in[4], dt + 1);

    // 2) fused extraction + upconvert
    ConvArgs ca{};
    int ne = 0;
    auto addc = [&](const void* s, float* d, int n) {
        ca.src[ne] = s; ca.dst[ne] = d; ca.n[ne] = n; ne++;
    };
    addc(d_in[0], Xf, N_ * 64);  addc(d_in[1], Zf, E_ * 16);
    addc(d_in[5], W1f, 8192);   addc(d_in[6], p1f, 16);   addc(d_in[7], b1f, 128);
    addc(d_in[8], Wf1f, 8192);  addc(d_in[9], g1f, 128);  addc(d_in[10], be1f, 128);
    addc(d_in[11], W2f, 256);   addc(d_in[12], p2f, 256); addc(d_in[13], b2f, 16);
    addc(d_in[14], Wf2f, 256);  addc(d_in[15], g2f, 16);  addc(d_in[16], be2f, 16);
    addc(d_in[17], W3f, 32768); addc(d_in[18], p3f, 32);  addc(d_in[19], b3f, 128);
    addc(d_in[20], W4f, 512);   addc(d_in[21], p4f, 128); addc(d_in[22], b4f, 16);
    addc(d_in[23], W5f, 16384); addc(d_in[24], p5f, 16);  addc(d_in[25], b5f, 128);
    int nb = 0;
    for (int e = 0; e < ne; e++) {
        ca.first[e] = nb;
        int k = (ca.n[e] + CHUNK - 1) / CHUNK;
        for (int j = 0; j < k; j++) ca.blk_entry[nb++] = (unsigned char)e;
    }

    GArgs a{d_in[4], d_in[3], d_in[2], dt,
            tcnt, trows, tvals, avc, avj, avv, aec, aej, aev,
            eav, eprod, d1, d2, d3, aea1, aea2, colmax1, colmax2,
            s_n1, s_n2, Xf, Zf,
            W1f, p1f, b1f, Wf1f, g1f, be1f,
            W2f, p2f, b2f, Wf2f, g2f, be2f,
            W3f, p3f, b3f, W4f, p4f, b4f,
            W5f, p5f, b5f,
            X1F1, F2b, HW, HeW, HeW2, X3, d_out};

    k_extract_all<<<1792 + nb, 256, 0, stream>>>(a, ca);

    // 3) pipeline: 8 stream-ordered batched dispatches
    k_stageA<<<576, 128, 0, stream>>>(a);
    k_node1<<<N_, 128, 0, stream>>>(a);
    k_stageC<<<2560, 128, 0, stream>>>(a);
    k_edge1<<<E_ / 4, 256, 0, stream>>>(a);
    k_node3<<<N_, 128, 0, stream>>>(a);
    k_stageF<<<2560, 128, 0, stream>>>(a);
    k_edge2<<<E_ / 4, 256, 0, stream>>>(a);
    k_node5<<<N_, 128, 0, stream>>>(a);
}

// Round 6
// 254.967 us; speedup vs baseline: 1.0006x; 1.0006x over previous
//
#include <hip/hip_runtime.h>
#include <hip/hip_bf16.h>
#include <hip/hip_cooperative_groups.h>

namespace cg = cooperative_groups;
using bf16 = __hip_bfloat16;

constexpr int N_ = 2048;    // nodes
constexpr int E_ = 4096;    // edges
constexpr int CAP = 64;     // max nnz per adjacency row

__device__ __forceinline__ void load8(const void* p, long long base, int isbf, float* f) {
    if (isbf) {
        uint4 u = *(const uint4*)((const unsigned short*)p + base);
        unsigned w0 = u.x, w1 = u.y, w2 = u.z, w3 = u.w;
        f[0] = __uint_as_float(w0 << 16); f[1] = __uint_as_float(w0 & 0xffff0000u);
        f[2] = __uint_as_float(w1 << 16); f[3] = __uint_as_float(w1 & 0xffff0000u);
        f[4] = __uint_as_float(w2 << 16); f[5] = __uint_as_float(w2 & 0xffff0000u);
        f[6] = __uint_as_float(w3 << 16); f[7] = __uint_as_float(w3 & 0xffff0000u);
    } else {
        const float4* q = (const float4*)((const float*)p + base);
        float4 a = q[0], b = q[1];
        f[0] = a.x; f[1] = a.y; f[2] = a.z; f[3] = a.w;
        f[4] = b.x; f[5] = b.y; f[6] = b.z; f[7] = b.w;
    }
}

constexpr int NCONV = 23;
constexpr int CHUNK = 8192;
struct ConvArgs {
    const void* src[NCONV];
    float* dst[NCONV];
    int n[NCONV];
    int first[NCONV];
    unsigned char blk_entry[64];
    int nb;
};

struct GArgs {
    const void* T; const void* adjV; const void* adjE;
    int* dt;
    int* tcnt; int* trows; float* tvals;
    int* avc; int* avj; float* avv;
    int* aec; int* aej; float* aev;
    int* eav; float* eprod;
    float *d1, *d2, *d3;
    float *aea1, *aea2, *colmax1, *colmax2;
    float *s_n1, *s_n2;
    float *Xf, *Zf;
    float *W1f, *p1f, *b1f, *Wf1f, *g1f, *be1f;
    float *W2f, *p2f, *b2f, *Wf2f, *g2f, *be2f;
    float *W3f, *p3f, *b3f, *W4f, *p4f, *b4f;
    float *W5f, *p5f, *b5f;
    float *X1F1, *F2, *HW, *HeW, *HeW2, *X3;
    void* out;
    int zero16;                     // uint4 count of zero-init block
};

// INLINE (noinline forces ABI frame + scratch spill: +216 MB HBM, R2)
__device__ __forceinline__ void emit_one(const GArgs& a, int region,
                                         long long idx, float v) {
    if (region == 0) {              // T: N x E
        int e = (int)(idx & (E_ - 1));
        int n = (int)(idx >> 12);
        int p = atomicAdd(&a.tcnt[e], 1);
        if (p < 2) { a.trows[e * 2 + p] = n; a.tvals[e * 2 + p] = v; }
    } else if (region == 1) {       // adjV: N x N
        int row = (int)(idx >> 11), col = (int)(idx & (N_ - 1));
        int s = atomicAdd(&a.avc[row], 1);
        if (s < CAP) { a.avj[row * CAP + s] = col; a.avv[row * CAP + s] = v; }
    } else {                        // adjE: E x E
        int row = (int)(idx >> 12), col = (int)(idx & (E_ - 1));
        int s = atomicAdd(&a.aec[row], 1);
        if (s < CAP) { a.aej[row * CAP + s] = col; a.aev[row * CAP + s] = v; }
    }
}

__device__ __forceinline__ void adjA_slot(const GArgs& a, int k, const float* sn,
                                          float* aea, float* colmax) {
    int e = k >> 6, s = k & 63;
    if (s >= min(a.aec[e], CAP)) return;
    int f = a.aej[k];
    float M;
    if (e == f) {
        M = 1.f;
    } else {
        M = 0.f;
        int ce = min(a.tcnt[e], 2), cf = min(a.tcnt[f], 2);
        for (int x = 0; x < ce; x++) {
            int nx = a.trows[2 * e + x]; float ux = a.tvals[2 * e + x];
            for (int y = 0; y < cf; y++)
                if (a.trows[2 * f + y] == nx) M += ux * a.tvals[2 * f + y] * sn[nx];
        }
    }
    float v = M * a.aev[k];
    aea[k] = v;
    if (v > 0.f) atomicMax((int*)&colmax[f], __float_as_int(v));
}

// edge SpMM + gate + scatter (+ optional W4 rowmat). One 64-lane wave per edge e.
__device__ __forceinline__ void edge_work(const GArgs& a, int e, int ln,
                                          const float* aea, const float* colmax,
                                          const float* Hsrc, const float* bia,
                                          const float* gate, const float* fsrc,
                                          float* dd, float* Hdst, int gate2) {
    int sub = ln >> 4, c = ln & 15;
    float acc = 0.f;
    int n = min(a.aec[e], CAP);
    for (int s = sub; s < n; s += 4) {
        int idx = e * CAP + s;
        int f = a.aej[idx];
        float cm = colmax[f];
        float nv = (cm != 0.f) ? aea[idx] / cm : 0.f;
        acc += nv * Hsrc[(long long)f * 16 + c];
    }
    acc += __shfl_xor(acc, 16);
    acc += __shfl_xor(acc, 32);
    float tot = fmaxf(bia[c] + acc, 0.f);
    float f2 = gate2 ? fsrc[(long long)e * 16 + c] : 0.f;
    float v = tot * gate[c] + (gate2 ? f2 * gate[16 + c] : 0.f);
#pragma unroll
    for (int m = 1; m < 16; m <<= 1) v += __shfl_xor(v, m);
    if (ln == 0) {
        float ep = a.eprod[e];
        if (ep != 0.f) {
            float cc = ep * v;
            int i1 = a.eav[2 * e], i2 = a.eav[2 * e + 1];
            if (i1 >= 0) unsafeAtomicAdd(&dd[i1], a.avv[i1] * cc);
            if (i2 >= 0) unsafeAtomicAdd(&dd[i2], a.avv[i2] * cc);
        }
    }
    if (Hdst) {
        float o = 0.f;
#pragma unroll
        for (int k = 0; k < 16; k++) {
            o += __shfl(tot, k, 16) * a.W4f[k * 16 + c];
            o += __shfl(f2, k, 16) * a.W4f[(16 + k) * 16 + c];
        }
        if (ln < 16) Hdst[(long long)e * 16 + c] = o;
    }
}

// node apply for mega (two 128-thread halves per block; h = half, tt = channel)
__device__ __forceinline__ void node_work(const GArgs& a, int i, int tt, int h,
                                          const float* bia, const float* dd,
                                          float* xout, int xstride,
                                          const float* g0, const float* g1s,
                                          float* sn, float* sm, int dorelu) {
    float acc = bia[tt];
    int n = min(a.avc[i], CAP);
    for (int s = 0; s < n; s++) {
        int idx = i * CAP + s;
        int col = a.avj[idx];
        float co = (col == i) ? a.avv[idx] : dd[idx];
        acc += co * a.HW[(long long)col * 128 + tt];
    }
    if (dorelu) acc = fmaxf(acc, 0.f);
    xout[(long long)i * xstride + tt] = acc;
    float v = acc * g0[tt];
    if (g1s) v += a.X1F1[(long long)i * 256 + 128 + tt] * g1s[tt];
    for (int o = 32; o > 0; o >>= 1) v += __shfl_down(v, o);
    if ((tt & 63) == 0) sm[h * 2 + (tt >> 6)] = v;
    __syncthreads();
    if (tt == 0) sn[i] = sm[h * 2] + sm[h * 2 + 1];
    __syncthreads();
}

// edge map + gate p1 + scatter d1 (per-edge thread)
__device__ __forceinline__ void edgemap_work(const GArgs& a, int e) {
    if (a.tcnt[e] < 2) {
        a.eav[2 * e] = -1; a.eav[2 * e + 1] = -1; a.eprod[e] = 0.f;
        return;
    }
    int p = a.trows[2 * e], q = a.trows[2 * e + 1];
    int ia = -1, ib = -1;
    int np = min(a.avc[p], CAP), nq = min(a.avc[q], CAP);
    for (int s = 0; s < np; s++) if (a.avj[p * CAP + s] == q) { ia = p * CAP + s; break; }
    for (int s = 0; s < nq; s++) if (a.avj[q * CAP + s] == p) { ib = q * CAP + s; break; }
    float ep = a.tvals[2 * e] * a.tvals[2 * e + 1];
    a.eav[2 * e] = ia; a.eav[2 * e + 1] = ib; a.eprod[e] = ep;
    const float4* zr = (const float4*)(a.Zf + (long long)e * 16);
    const float4* pr = (const float4*)a.p1f;
    float s = 0.f;
#pragma unroll
    for (int qq = 0; qq < 4; qq++) {
        float4 hh = zr[qq], pp = pr[qq];
        s += hh.x * pp.x + hh.y * pp.y + hh.z * pp.z + hh.w * pp.w;
    }
    float c = ep * s;
    if (ia >= 0) unsafeAtomicAdd(&a.d1[ia], a.avv[ia] * c);
    if (ib >= 0) unsafeAtomicAdd(&a.d1[ib], a.avv[ib] * c);
}

// edge feat: HeW = relu(Z)@W2 ; F2 = relu(LN(Z@Wf2)) (per-edge thread)
__device__ __forceinline__ void edgefeat_work(const GArgs& a, int e) {
    const float4* zr = (const float4*)(a.Zf + (long long)e * 16);
    float zv[16];
    float4 z0 = zr[0], z1 = zr[1], z2 = zr[2], z3 = zr[3];
    zv[0] = z0.x; zv[1] = z0.y; zv[2] = z0.z; zv[3] = z0.w;
    zv[4] = z1.x; zv[5] = z1.y; zv[6] = z1.z; zv[7] = z1.w;
    zv[8] = z2.x; zv[9] = z2.y; zv[10] = z2.z; zv[11] = z2.w;
    zv[12] = z3.x; zv[13] = z3.y; zv[14] = z3.z; zv[15] = z3.w;
    float hw[16], f2[16];
#pragma unroll
    for (int c = 0; c < 16; c++) { hw[c] = 0.f; f2[c] = 0.f; }
#pragma unroll
    for (int k = 0; k < 16; k++) {
        float ar = fmaxf(zv[k], 0.f), az = zv[k];
#pragma unroll
        for (int c = 0; c < 16; c++) {
            hw[c] += ar * a.W2f[k * 16 + c];
            f2[c] += az * a.Wf2f[k * 16 + c];
        }
    }
    float m = 0.f;
#pragma unroll
    for (int c = 0; c < 16; c++) m += f2[c];
    m *= (1.f / 16.f);
    float var = 0.f;
#pragma unroll
    for (int c = 0; c < 16; c++) { float d = f2[c] - m; var += d * d; }
    var *= (1.f / 16.f);
    float rs = rsqrtf(var + 1e-5f);
#pragma unroll
    for (int c = 0; c < 16; c++)
        f2[c] = fmaxf((f2[c] - m) * rs * a.g2f[c] + a.be2f[c], 0.f);
    float4* ho = (float4*)(a.HeW + (long long)e * 16);
    ho[0] = make_float4(hw[0], hw[1], hw[2], hw[3]);
    ho[1] = make_float4(hw[4], hw[5], hw[6], hw[7]);
    ho[2] = make_float4(hw[8], hw[9], hw[10], hw[11]);
    ho[3] = make_float4(hw[12], hw[13], hw[14], hw[15]);
    float4* fo = (float4*)(a.F2 + (long long)e * 16);
    fo[0] = make_float4(f2[0], f2[1], f2[2], f2[3]);
    fo[1] = make_float4(f2[4], f2[5], f2[6], f2[7]);
    fo[2] = make_float4(f2[8], f2[9], f2[10], f2[11]);
    fo[3] = make_float4(f2[12], f2[13], f2[14], f2[15]);
}

// ---- MEGA kernel: all phases, 1024 blocks x 256 threads, cooperative.
// launch_bounds(256,4): 4 waves/EU => 4 blocks/CU => capacity 1024 (VGPR<=128,
// comfortably met). Launched ONLY if the runtime occupancy query agrees.
__global__ void __launch_bounds__(256, 4) k_mega(GArgs a, ConvArgs ca) {
    cg::grid_group grid = cg::this_grid();
    __shared__ float shmem[2048];
    __shared__ float red[16];
    int b = blockIdx.x, t = threadIdx.x;
    int gtid = b * 256 + t;                 // 262144 threads
    int h = t >> 7, tt = t & 127;           // half / channel

    // phase 0: zero workspace init block (replaces hipMemsetAsync)
    {
        uint4* z = (uint4*)a.dt;
        for (int i = gtid; i < a.zero16; i += 262144)
            z[i] = make_uint4(0u, 0u, 0u, 0u);
    }
    grid.sync();

    // phase 1: dtype detect (first 2 MB of T)
    if (gtid < 131072) {
        uint4 u = ((const uint4*)a.T)[gtid];
        if ((u.x | u.y | u.z | u.w) & 0xFFFFu) a.dt[1] = 1;
    }
    grid.sync();
    int isbf = a.dt[1];

    // phase 2: sparse extraction (grid-stride, 16 elems/chunk) + upconvert
    {
        for (int k = gtid; k < 1835008; k += 262144) {
            int region; const void* src; long long K;
            if (k < 524288)      { region = 0; src = a.T;    K = (long long)k << 4; }
            else if (k < 786432) { region = 1; src = a.adjV; K = (long long)(k - 524288) << 4; }
            else                 { region = 2; src = a.adjE; K = (long long)(k - 786432) << 4; }
            float f[16];
            load8(src, K, isbf, f); load8(src, K + 8, isbf, f + 8);
#pragma unroll
            for (int j = 0; j < 16; j++)
                if (f[j] != 0.f) emit_one(a, region, K + j, f[j]);
        }
        if (b < ca.nb) {
            int e = ca.blk_entry[b];
            int off = (b - ca.first[e]) * CHUNK;
            int n = ca.n[e];
            const void* src = ca.src[e];
            float* dst = ca.dst[e];
            int lim = min(off + CHUNK, n);
            for (int i = off + t * 8; i < lim; i += 256 * 8) {
                float f[8]; load8(src, i, isbf, f);
                float4* d = (float4*)(dst + i);
                d[0] = make_float4(f[0], f[1], f[2], f[3]);
                d[1] = make_float4(f[4], f[5], f[6], f[7]);
            }
        }
    }
    grid.sync();

    // phase A: edge_map | edge_feat | fused W1&Wf1 gemm+LN (8 rows/block, 2 halves)
    if (b < 16) {
        edgemap_work(a, b * 256 + t);
    } else if (b < 32) {
        edgefeat_work(a, (b - 16) * 256 + t);
    } else if (b < 288) {
        int r0 = (b - 32) * 8 + h * 4;
        float* sh = shmem + h * 256;
        float* redh = red + h * 8;
        for (int j = tt; j < 256; j += 128) sh[j] = a.Xf[(long long)r0 * 64 + j];
        __syncthreads();
        float h0 = 0.f, h1 = 0.f, h2 = 0.f, h3 = 0.f;
        float f0 = 0.f, f1 = 0.f, f2 = 0.f, f3 = 0.f;
#pragma unroll 8
        for (int k = 0; k < 64; k++) {
            float w1 = a.W1f[k * 128 + tt], wf = a.Wf1f[k * 128 + tt];
            float x0 = sh[k], x1 = sh[64 + k], x2 = sh[128 + k], x3 = sh[192 + k];
            h0 += x0 * w1; h1 += x1 * w1; h2 += x2 * w1; h3 += x3 * w1;
            f0 += x0 * wf; f1 += x1 * wf; f2 += x2 * wf; f3 += x3 * wf;
        }
        a.HW[(long long)(r0 + 0) * 128 + tt] = h0;
        a.HW[(long long)(r0 + 1) * 128 + tt] = h1;
        a.HW[(long long)(r0 + 2) * 128 + tt] = h2;
        a.HW[(long long)(r0 + 3) * 128 + tt] = h3;
        float s0 = f0, s1 = f1, s2 = f2, s3 = f3;
        for (int o = 32; o > 0; o >>= 1) {
            s0 += __shfl_down(s0, o); s1 += __shfl_down(s1, o);
            s2 += __shfl_down(s2, o); s3 += __shfl_down(s3, o);
        }
        if ((tt & 63) == 0) {
            int w4 = (tt >> 6) * 4;
            redh[w4] = s0; redh[w4 + 1] = s1; redh[w4 + 2] = s2; redh[w4 + 3] = s3;
        }
        __syncthreads();
        float m0 = (redh[0] + redh[4]) * (1.f / 128.f);
        float m1 = (redh[1] + redh[5]) * (1.f / 128.f);
        float m2 = (redh[2] + redh[6]) * (1.f / 128.f);
        float m3 = (redh[3] + redh[7]) * (1.f / 128.f);
        __syncthreads();
        float d0 = f0 - m0, d1 = f1 - m1, d2 = f2 - m2, d3 = f3 - m3;
        s0 = d0 * d0; s1 = d1 * d1; s2 = d2 * d2; s3 = d3 * d3;
        for (int o = 32; o > 0; o >>= 1) {
            s0 += __shfl_down(s0, o); s1 += __shfl_down(s1, o);
            s2 += __shfl_down(s2, o); s3 += __shfl_down(s3, o);
        }
        if ((tt & 63) == 0) {
            int w4 = (tt >> 6) * 4;
            redh[w4] = s0; redh[w4 + 1] = s1; redh[w4 + 2] = s2; redh[w4 + 3] = s3;
        }
        __syncthreads();
        float v0 = (redh[0] + redh[4]) * (1.f / 128.f);
        float v1 = (redh[1] + redh[5]) * (1.f / 128.f);
        float v2 = (redh[2] + redh[6]) * (1.f / 128.f);
        float v3 = (redh[3] + redh[7]) * (1.f / 128.f);
        float g = a.g1f[tt], be = a.be1f[tt];
        a.X1F1[(long long)(r0 + 0) * 256 + 128 + tt] = fmaxf(d0 * rsqrtf(v0 + 1e-5f) * g + be, 0.f);
        a.X1F1[(long long)(r0 + 1) * 256 + 128 + tt] = fmaxf(d1 * rsqrtf(v1 + 1e-5f) * g + be, 0.f);
        a.X1F1[(long long)(r0 + 2) * 256 + 128 + tt] = fmaxf(d2 * rsqrtf(v2 + 1e-5f) * g + be, 0.f);
        a.X1F1[(long long)(r0 + 3) * 256 + 128 + tt] = fmaxf(d3 * rsqrtf(v3 + 1e-5f) * g + be, 0.f);
    }
    grid.sync();

    // phase B: node1 + gate p2 -> s_n1  (2 nodes/block)
    node_work(a, b * 2 + h, tt, h, a.b1f, a.d1, a.X1F1, 256,
              a.p2f, a.p2f + 128, a.s_n1, red, 1);
    grid.sync();

    // phase C: adjA1 (1 slot/thread) | gemm W3 (blocks 0..255, 8 rows)
    adjA_slot(a, gtid, a.s_n1, a.aea1, a.colmax1);
    if (b < 256) {
        int r0 = b * 8 + h * 4;
        float* sh = shmem + h * 1024;
        for (int j = tt; j < 1024; j += 128) sh[j] = a.X1F1[(long long)r0 * 256 + j];
        __syncthreads();
        float a0 = 0.f, a1 = 0.f, a2 = 0.f, a3 = 0.f;
        for (int k = 0; k < 256; k++) {
            float w = a.W3f[k * 128 + tt];
            a0 += sh[k] * w; a1 += sh[256 + k] * w;
            a2 += sh[512 + k] * w; a3 += sh[768 + k] * w;
        }
        a.HW[(long long)r0 * 128 + tt] = a0;
        a.HW[(long long)(r0 + 1) * 128 + tt] = a1;
        a.HW[(long long)(r0 + 2) * 128 + tt] = a2;
        a.HW[(long long)(r0 + 3) * 128 + tt] = a3;
    }
    grid.sync();

    // phase D: edge1 (4 waves/block, e = b*4 + wave)
    edge_work(a, b * 4 + (t >> 6), t & 63, a.aea1, a.colmax1, a.HeW,
              a.b2f, a.p3f, a.F2, a.d2, a.HeW2, 1);
    grid.sync();

    // phase E: node3 + gate p4 -> s_n2
    node_work(a, b * 2 + h, tt, h, a.b3f, a.d2, a.X3, 128,
              a.p4f, nullptr, a.s_n2, red, 1);
    grid.sync();

    // phase F: adjA2 | gemm W5 (blocks 0..255, 8 rows)
    adjA_slot(a, gtid, a.s_n2, a.aea2, a.colmax2);
    if (b < 256) {
        int r0 = b * 8 + h * 4;
        float* sh = shmem + h * 512;
        for (int j = tt; j < 512; j += 128) sh[j] = a.X3[(long long)r0 * 128 + j];
        __syncthreads();
        float a0 = 0.f, a1 = 0.f, a2 = 0.f, a3 = 0.f;
        for (int k = 0; k < 128; k++) {
            float w = a.W5f[k * 128 + tt];
            a0 += sh[k] * w; a1 += sh[128 + k] * w;
            a2 += sh[256 + k] * w; a3 += sh[384 + k] * w;
        }
        a.HW[(long long)r0 * 128 + tt] = a0;
        a.HW[(long long)(r0 + 1) * 128 + tt] = a1;
        a.HW[(long long)(r0 + 2) * 128 + tt] = a2;
        a.HW[(long long)(r0 + 3) * 128 + tt] = a3;
    }
    grid.sync();

    // phase G: edge2
    edge_work(a, b * 4 + (t >> 6), t & 63, a.aea2, a.colmax2, a.HeW2,
              a.b4f, a.p5f, nullptr, a.d3, nullptr, 0);
    grid.sync();

    // phase H: node5 -> out (2 nodes/block)
    {
        int i = b * 2 + h;
        float acc = a.b5f[tt];
        int n = min(a.avc[i], CAP);
        for (int s = 0; s < n; s++) {
            int idx = i * CAP + s;
            int col = a.avj[idx];
            float co = (col == i) ? a.avv[idx] : a.d3[idx];
            acc += co * a.HW[(long long)col * 128 + tt];
        }
        if (isbf) ((bf16*)a.out)[(long long)i * 128 + tt] = __float2bfloat16(acc);
        else      ((float*)a.out)[(long long)i * 128 + tt] = acc;
    }
}

// ================= FALLBACK: proven R3 multi-kernel pipeline =================

__global__ void k_detect(const unsigned int* __restrict__ t32, int* __restrict__ flag) {
    long long i = (long long)(blockIdx.x * blockDim.x + threadIdx.x) * 4;
    uint4 u = *(const uint4*)(t32 + i);
    if ((u.x | u.y | u.z | u.w) & 0xFFFFu) *flag = 1;
}

__device__ __forceinline__ void emit_bf2(const GArgs& a, int region,
                                         long long e0, unsigned w) {
    if (w & 0xFFFFu) emit_one(a, region, e0,     __uint_as_float(w << 16));
    if (w >> 16)     emit_one(a, region, e0 + 1, __uint_as_float(w & 0xffff0000u));
}

__global__ void __launch_bounds__(256) k_extract_fb(GArgs a, ConvArgs ca) {
    int b = blockIdx.x, t = threadIdx.x;
    int isbf = a.dt[1];
    if (b < 1792) {
        int region; const void* src; long long elem0;
        if (b < 512)      { region = 0; src = a.T;    elem0 = (long long)b << 14; }
        else if (b < 768) { region = 1; src = a.adjV; elem0 = (long long)(b - 512) << 14; }
        else              { region = 2; src = a.adjE; elem0 = (long long)(b - 768) << 14; }
        int ln = t & 63;
        long long wbase = elem0 + (long long)(t >> 6) * 4096;
        if (isbf) {
            const uint4* q = (const uint4*)((const unsigned short*)src + wbase);
            uint4 u[8];
#pragma unroll
            for (int j = 0; j < 8; j++) u[j] = q[j * 64 + ln];
            unsigned any = 0;
#pragma unroll
            for (int j = 0; j < 8; j++) any |= u[j].x | u[j].y | u[j].z | u[j].w;
            if (any) {
#pragma unroll
                for (int j = 0; j < 8; j++) {
                    long long eb = wbase + (long long)(j * 64 + ln) * 8;
                    if (u[j].x) emit_bf2(a, region, eb,     u[j].x);
                    if (u[j].y) emit_bf2(a, region, eb + 2, u[j].y);
                    if (u[j].z) emit_bf2(a, region, eb + 4, u[j].z);
                    if (u[j].w) emit_bf2(a, region, eb + 6, u[j].w);
                }
            }
        } else {
            const uint4* q = (const uint4*)((const float*)src + wbase);
#pragma unroll
            for (int hh = 0; hh < 2; hh++) {
                uint4 u[8];
#pragma unroll
                for (int j = 0; j < 8; j++) u[j] = q[hh * 512 + j * 64 + ln];
                unsigned any = 0;
#pragma unroll
                for (int j = 0; j < 8; j++) any |= u[j].x | u[j].y | u[j].z | u[j].w;
                if (any) {
#pragma unroll
                    for (int j = 0; j < 8; j++) {
                        long long eb = wbase + (long long)(hh * 512 + j * 64 + ln) * 4;
                        if (u[j].x) emit_one(a, region, eb,     __uint_as_float(u[j].x));
                        if (u[j].y) emit_one(a, region, eb + 1, __uint_as_float(u[j].y));
                        if (u[j].z) emit_one(a, region, eb + 2, __uint_as_float(u[j].z));
                        if (u[j].w) emit_one(a, region, eb + 3, __uint_as_float(u[j].w));
                    }
                }
            }
        }
    } else {
        int gb = b - 1792;
        int e = ca.blk_entry[gb];
        int off = (gb - ca.first[e]) * CHUNK;
        int n = ca.n[e];
        const void* src = ca.src[e];
        float* dst = ca.dst[e];
        int lim = min(off + CHUNK, n);
        for (int i = off + t * 8; i < lim; i += 256 * 8) {
            float f[8]; load8(src, i, isbf, f);
            float4* d = (float4*)(dst + i);
            d[0] = make_float4(f[0], f[1], f[2], f[3]);
            d[1] = make_float4(f[4], f[5], f[6], f[7]);
        }
    }
}

__global__ void __launch_bounds__(128) k_stageA(GArgs a) {
    __shared__ float lds[256];
    __shared__ float red[8];
    int b = blockIdx.x, t = threadIdx.x;
    if (b < 32) {
        edgemap_work(a, b * 128 + t);
    } else if (b < 64) {
        edgefeat_work(a, (b - 32) * 128 + t);
    } else {
        int r0 = (b - 64) * 4;
        for (int j = t; j < 256; j += 128) lds[j] = a.Xf[(long long)r0 * 64 + j];
        __syncthreads();
        float h0 = 0.f, h1 = 0.f, h2 = 0.f, h3 = 0.f;
        float f0 = 0.f, f1 = 0.f, f2 = 0.f, f3 = 0.f;
#pragma unroll 8
        for (int k = 0; k < 64; k++) {
            float w1 = a.W1f[k * 128 + t], wf = a.Wf1f[k * 128 + t];
            float x0 = lds[k], x1 = lds[64 + k], x2 = lds[128 + k], x3 = lds[192 + k];
            h0 += x0 * w1; h1 += x1 * w1; h2 += x2 * w1; h3 += x3 * w1;
            f0 += x0 * wf; f1 += x1 * wf; f2 += x2 * wf; f3 += x3 * wf;
        }
        a.HW[(long long)(r0 + 0) * 128 + t] = h0;
        a.HW[(long long)(r0 + 1) * 128 + t] = h1;
        a.HW[(long long)(r0 + 2) * 128 + t] = h2;
        a.HW[(long long)(r0 + 3) * 128 + t] = h3;
        float s0 = f0, s1 = f1, s2 = f2, s3 = f3;
        for (int o = 32; o > 0; o >>= 1) {
            s0 += __shfl_down(s0, o); s1 += __shfl_down(s1, o);
            s2 += __shfl_down(s2, o); s3 += __shfl_down(s3, o);
        }
        if ((t & 63) == 0) {
            int w4 = (t >> 6) * 4;
            red[w4] = s0; red[w4 + 1] = s1; red[w4 + 2] = s2; red[w4 + 3] = s3;
        }
        __syncthreads();
        float m0 = (red[0] + red[4]) * (1.f / 128.f);
        float m1 = (red[1] + red[5]) * (1.f / 128.f);
        float m2 = (red[2] + red[6]) * (1.f / 128.f);
        float m3 = (red[3] + red[7]) * (1.f / 128.f);
        __syncthreads();
        float d0 = f0 - m0, d1 = f1 - m1, d2 = f2 - m2, d3 = f3 - m3;
        s0 = d0 * d0; s1 = d1 * d1; s2 = d2 * d2; s3 = d3 * d3;
        for (int o = 32; o > 0; o >>= 1) {
            s0 += __shfl_down(s0, o); s1 += __shfl_down(s1, o);
            s2 += __shfl_down(s2, o); s3 += __shfl_down(s3, o);
        }
        if ((t & 63) == 0) {
            int w4 = (t >> 6) * 4;
            red[w4] = s0; red[w4 + 1] = s1; red[w4 + 2] = s2; red[w4 + 3] = s3;
        }
        __syncthreads();
        float v0 = (red[0] + red[4]) * (1.f / 128.f);
        float v1 = (red[1] + red[5]) * (1.f / 128.f);
        float v2 = (red[2] + red[6]) * (1.f / 128.f);
        float v3 = (red[3] + red[7]) * (1.f / 128.f);
        float g = a.g1f[t], be = a.be1f[t];
        a.X1F1[(long long)(r0 + 0) * 256 + 128 + t] = fmaxf(d0 * rsqrtf(v0 + 1e-5f) * g + be, 0.f);
        a.X1F1[(long long)(r0 + 1) * 256 + 128 + t] = fmaxf(d1 * rsqrtf(v1 + 1e-5f) * g + be, 0.f);
        a.X1F1[(long long)(r0 + 2) * 256 + 128 + t] = fmaxf(d2 * rsqrtf(v2 + 1e-5f) * g + be, 0.f);
        a.X1F1[(long long)(r0 + 3) * 256 + 128 + t] = fmaxf(d3 * rsqrtf(v3 + 1e-5f) * g + be, 0.f);
    }
}

__global__ void __launch_bounds__(128) k_node1(GArgs a) {
    __shared__ float sm[4];
    node_work(a, blockIdx.x, threadIdx.x, 0, a.b1f, a.d1, a.X1F1, 256,
              a.p2f, a.p2f + 128, a.s_n1, sm, 1);
}

__global__ void __launch_bounds__(128) k_stageC(GArgs a) {
    __shared__ float lds[1024];
    int b = blockIdx.x, t = threadIdx.x;
    if (b < 2048) {
        adjA_slot(a, b * 128 + t, a.s_n1, a.aea1, a.colmax1);
    } else {
        int r0 = (b - 2048) * 4;
        for (int j = t; j < 1024; j += 128) lds[j] = a.X1F1[(long long)r0 * 256 + j];
        __syncthreads();
        float a0 = 0.f, a1 = 0.f, a2 = 0.f, a3 = 0.f;
        for (int k = 0; k < 256; k++) {
            float w = a.W3f[k * 128 + t];
            a0 += lds[k] * w; a1 += lds[256 + k] * w;
            a2 += lds[512 + k] * w; a3 += lds[768 + k] * w;
        }
        a.HW[(long long)r0 * 128 + t] = a0;
        a.HW[(long long)(r0 + 1) * 128 + t] = a1;
        a.HW[(long long)(r0 + 2) * 128 + t] = a2;
        a.HW[(long long)(r0 + 3) * 128 + t] = a3;
    }
}

__global__ void __launch_bounds__(256) k_edge1(GArgs a) {
    edge_work(a, (blockIdx.x * 256 + threadIdx.x) >> 6, threadIdx.x & 63,
              a.aea1, a.colmax1, a.HeW, a.b2f, a.p3f, a.F2, a.d2, a.HeW2, 1);
}

__global__ void __launch_bounds__(128) k_node3(GArgs a) {
    __shared__ float sm[4];
    node_work(a, blockIdx.x, threadIdx.x, 0, a.b3f, a.d2, a.X3, 128,
              a.p4f, nullptr, a.s_n2, sm, 1);
}

__global__ void __launch_bounds__(128) k_stageF(GArgs a) {
    __shared__ float lds[512];
    int b = blockIdx.x, t = threadIdx.x;
    if (b < 2048) {
        adjA_slot(a, b * 128 + t, a.s_n2, a.aea2, a.colmax2);
    } else {
        int r0 = (b - 2048) * 4;
        for (int j = t; j < 512; j += 128) lds[j] = a.X3[(long long)r0 * 128 + j];
        __syncthreads();
        float a0 = 0.f, a1 = 0.f, a2 = 0.f, a3 = 0.f;
        for (int k = 0; k < 128; k++) {
            float w = a.W5f[k * 128 + t];
            a0 += lds[k] * w; a1 += lds[128 + k] * w;
            a2 += lds[256 + k] * w; a3 += lds[384 + k] * w;
        }
        a.HW[(long long)r0 * 128 + t] = a0;
        a.HW[(long long)(r0 + 1) * 128 + t] = a1;
        a.HW[(long long)(r0 + 2) * 128 + t] = a2;
        a.HW[(long long)(r0 + 3) * 128 + t] = a3;
    }
}

__global__ void __launch_bounds__(256) k_edge2(GArgs a) {
    edge_work(a, (blockIdx.x * 256 + threadIdx.x) >> 6, threadIdx.x & 63,
              a.aea2, a.colmax2, a.HeW2, a.b4f, a.p5f, nullptr, a.d3, nullptr, 0);
}

__global__ void __launch_bounds__(128) k_node5(GArgs a) {
    int i = blockIdx.x, c = threadIdx.x;
    float acc = a.b5f[c];
    int n = min(a.avc[i], CAP);
    for (int s = 0; s < n; s++) {
        int idx = i * CAP + s;
        int col = a.avj[idx];
        float co = (col == i) ? a.avv[idx] : a.d3[idx];
        acc += co * a.HW[(long long)col * 128 + c];
    }
    if (a.dt[1]) ((bf16*)a.out)[(long long)i * 128 + c] = __float2bfloat16(acc);
    else         ((float*)a.out)[(long long)i * 128 + c] = acc;
}

extern "C" void kernel_launch(void* const* d_in, const int* in_sizes, int n_in,
                              void* d_out, int out_size, void* d_ws, size_t ws_size,
                              hipStream_t stream) {
    char* wsB = (char*)d_ws;
    size_t off = 0;
    auto alloc = [&](size_t bytes) -> void* {
        void* p = wsB + off;
        off += (bytes + 255) & ~(size_t)255;
        return p;
    };
    int*   dt      = (int*)alloc(2 * 4);
    int*   tcnt    = (int*)alloc(E_ * 4);
    int*   avc     = (int*)alloc(N_ * 4);
    int*   aec     = (int*)alloc(E_ * 4);
    float* colmax1 = (float*)alloc(E_ * 4);
    float* colmax2 = (float*)alloc(E_ * 4);
    float* d1      = (float*)alloc((size_t)N_ * CAP * 4);
    float* d2      = (float*)alloc((size_t)N_ * CAP * 4);
    float* d3      = (float*)alloc((size_t)N_ * CAP * 4);
    size_t zero_bytes = off;
    float* Xf  = (float*)alloc((size_t)N_ * 64 * 4);
    float* Zf  = (float*)alloc((size_t)E_ * 16 * 4);
    float* W1f = (float*)alloc(8192 * 4);  float* p1f = (float*)alloc(16 * 4);
    float* b1f = (float*)alloc(128 * 4);
    float* Wf1f = (float*)alloc(8192 * 4); float* g1f = (float*)alloc(128 * 4);
    float* be1f = (float*)alloc(128 * 4);
    float* W2f = (float*)alloc(256 * 4);   float* p2f = (float*)alloc(256 * 4);
    float* b2f = (float*)alloc(16 * 4);
    float* Wf2f = (float*)alloc(256 * 4);  float* g2f = (float*)alloc(16 * 4);
    float* be2f = (float*)alloc(16 * 4);
    float* W3f = (float*)alloc(32768 * 4); float* p3f = (float*)alloc(32 * 4);
    float* b3f = (float*)alloc(128 * 4);
    float* W4f = (float*)alloc(512 * 4);   float* p4f = (float*)alloc(128 * 4);
    float* b4f = (float*)alloc(16 * 4);
    float* W5f = (float*)alloc(16384 * 4); float* p5f = (float*)alloc(16 * 4);
    float* b5f = (float*)alloc(128 * 4);
    int*   trows  = (int*)alloc(E_ * 2 * 4);
    float* tvals  = (float*)alloc(E_ * 2 * 4);
    int*   avj    = (int*)alloc((size_t)N_ * CAP * 4);
    float* avv    = (float*)alloc((size_t)N_ * CAP * 4);
    int*   aej    = (int*)alloc((size_t)E_ * CAP * 4);
    float* aev    = (float*)alloc((size_t)E_ * CAP * 4);
    float* aea1   = (float*)alloc((size_t)E_ * CAP * 4);
    float* aea2   = (float*)alloc((size_t)E_ * CAP * 4);
    int*   eav    = (int*)alloc(E_ * 2 * 4);
    float* eprod  = (float*)alloc(E_ * 4);
    float* s_n1   = (float*)alloc(N_ * 4);
    float* s_n2   = (float*)alloc(N_ * 4);
    float* X1F1   = (float*)alloc((size_t)N_ * 256 * 4);
    float* F2b    = (float*)alloc((size_t)E_ * 16 * 4);
    float* HW     = (float*)alloc((size_t)N_ * 128 * 4);
    float* HeW    = (float*)alloc((size_t)E_ * 16 * 4);
    float* HeW2   = (float*)alloc((size_t)E_ * 16 * 4);
    float* X3     = (float*)alloc((size_t)N_ * 128 * 4);

    ConvArgs ca{};
    int ne = 0;
    auto addc = [&](const void* s, float* d, int n) {
        ca.src[ne] = s; ca.dst[ne] = d; ca.n[ne] = n; ne++;
    };
    addc(d_in[0], Xf, N_ * 64);  addc(d_in[1], Zf, E_ * 16);
    addc(d_in[5], W1f, 8192);   addc(d_in[6], p1f, 16);   addc(d_in[7], b1f, 128);
    addc(d_in[8], Wf1f, 8192);  addc(d_in[9], g1f, 128);  addc(d_in[10], be1f, 128);
    addc(d_in[11], W2f, 256);   addc(d_in[12], p2f, 256); addc(d_in[13], b2f, 16);
    addc(d_in[14], Wf2f, 256);  addc(d_in[15], g2f, 16);  addc(d_in[16], be2f, 16);
    addc(d_in[17], W3f, 32768); addc(d_in[18], p3f, 32);  addc(d_in[19], b3f, 128);
    addc(d_in[20], W4f, 512);   addc(d_in[21], p4f, 128); addc(d_in[22], b4f, 16);
    addc(d_in[23], W5f, 16384); addc(d_in[24], p5f, 16);  addc(d_in[25], b5f, 128);
    int nb = 0;
    for (int e = 0; e < ne; e++) {
        ca.first[e] = nb;
        int k = (ca.n[e] + CHUNK - 1) / CHUNK;
        for (int j = 0; j < k; j++) ca.blk_entry[nb++] = (unsigned char)e;
    }
    ca.nb = nb;

    GArgs a{d_in[4], d_in[3], d_in[2], dt,
            tcnt, trows, tvals, avc, avj, avv, aec, aej, aev,
            eav, eprod, d1, d2, d3, aea1, aea2, colmax1, colmax2,
            s_n1, s_n2, Xf, Zf,
            W1f, p1f, b1f, Wf1f, g1f, be1f,
            W2f, p2f, b2f, Wf2f, g2f, be2f,
            W3f, p3f, b3f, W4f, p4f, b4f,
            W5f, p5f, b5f,
            X1F1, F2b, HW, HeW, HeW2, X3, d_out,
            (int)(zero_bytes / 16)};

    // ---- try cooperative mega-kernel; verified gate + checked return code
    int maxb = 0;
    hipError_t qerr = hipOccupancyMaxActiveBlocksPerMultiprocessor(
        &maxb, (const void*)k_mega, 256, 0);
    if (qerr == hipSuccess && maxb >= 4) {      // 4 blk/CU x 256 CU >= 1024
        void* args[] = {(void*)&a, (void*)&ca};
        hipError_t lerr = hipLaunchCooperativeKernel(
            (const void*)k_mega, dim3(1024), dim3(256), args, 0, stream);
        if (lerr == hipSuccess) return;
    }

    // ---- fallback: proven R3 pipeline
    hipMemsetAsync(dt, 0, zero_bytes, stream);
    k_detect<<<512, 256, 0, stream>>>((const unsigned int*)d_in[4], dt + 1);
    k_extract_fb<<<1792 + nb, 256, 0, stream>>>(a, ca);
    k_stageA<<<576, 128, 0, stream>>>(a);
    k_node1<<<N_, 128, 0, stream>>>(a);
    k_stageC<<<2560, 128, 0, stream>>>(a);
    k_edge1<<<E_ / 4, 256, 0, stream>>>(a);
    k_node3<<<N_, 128, 0, stream>>>(a);
    k_stageF<<<2560, 128, 0, stream>>>(a);
    k_edge2<<<E_ / 4, 256, 0, stream>>>(a);
    k_node5<<<N_, 128, 0, stream>>>(a);
}

// Round 7
// 242.222 us; speedup vs baseline: 1.0533x; 1.0526x over previous
//
#include <hip/hip_runtime.h>
#include <hip/hip_bf16.h>

using bf16 = __hip_bfloat16;

constexpr int N_ = 2048;    // nodes
constexpr int E_ = 4096;    // edges
constexpr int CAP = 64;     // max nnz per adjacency row

__device__ __forceinline__ void unpack8(uint4 u, float* f) {
    unsigned w0 = u.x, w1 = u.y, w2 = u.z, w3 = u.w;
    f[0] = __uint_as_float(w0 << 16); f[1] = __uint_as_float(w0 & 0xffff0000u);
    f[2] = __uint_as_float(w1 << 16); f[3] = __uint_as_float(w1 & 0xffff0000u);
    f[4] = __uint_as_float(w2 << 16); f[5] = __uint_as_float(w2 & 0xffff0000u);
    f[6] = __uint_as_float(w3 << 16); f[7] = __uint_as_float(w3 & 0xffff0000u);
}

__device__ __forceinline__ void load8(const void* p, long long base, int isbf, float* f) {
    if (isbf) {
        uint4 u = *(const uint4*)((const unsigned short*)p + base);
        unpack8(u, f);
    } else {
        const float4* q = (const float4*)((const float*)p + base);
        float4 a = q[0], b = q[1];
        f[0] = a.x; f[1] = a.y; f[2] = a.z; f[3] = a.w;
        f[4] = b.x; f[5] = b.y; f[6] = b.z; f[7] = b.w;
    }
}

constexpr int NCONV = 23;
constexpr int CHUNK = 8192;
struct ConvArgs {
    const void* src[NCONV];
    float* dst[NCONV];
    int n[NCONV];
    int first[NCONV];
    unsigned char blk_entry[64];
};

struct GArgs {
    const void* T; const void* adjV; const void* adjE;
    int* dt;
    int* tcnt; int* trows; float* tvals;
    int* avc; int* avj; float* avv;
    int* aec; int* aej; float* aev;
    int* eav; float* eprod;
    float *d1, *d2, *d3;            // avco deltas (zeroed by k_init)
    float *aea1, *aea2, *colmax1, *colmax2;
    float *s_n1, *s_n2;
    float *Xf, *Zf;
    float *W1f, *p1f, *b1f, *Wf1f, *g1f, *be1f;
    float *W2f, *p2f, *b2f, *Wf2f, *g2f, *be2f;
    float *W3f, *p3f, *b3f, *W4f, *p4f, *b4f;
    float *W5f, *p5f, *b5f;
    float *X1F1, *F2, *HW, *HeW, *HeW2, *X3;
    void* out;
    int zero16;                     // uint4 count of zero-init block
};

// ---- k_init: fused workspace-zero + dtype detect (was 2 dispatches).
// blocks 0..511: detect over first 2 MB of T; blocks 512..1023: zero init block.
__global__ void __launch_bounds__(256) k_init(GArgs a) {
    int b = blockIdx.x, t = threadIdx.x;
    if (b < 512) {
        long long i = (long long)(b * 256 + t) * 4;
        uint4 u = *(const uint4*)((const unsigned int*)a.T + i);
        if ((u.x | u.y | u.z | u.w) & 0xFFFFu) a.dt[1] = 1;
    } else {
        uint4* z = (uint4*)a.dt;
        for (int i = (b - 512) * 256 + t; i < a.zero16; i += 512 * 256)
            z[i] = make_uint4(0u, 0u, 0u, 0u);
    }
}

// ---- rare-path emitter (INLINE — noinline forces an ABI frame + scratch
// spill of live loads: +216 MB HBM traffic measured in R2. Keep inline.)
__device__ __forceinline__ void emit_one(const GArgs& a, int region,
                                         long long idx, float v) {
    if (region == 0) {              // T: N x E
        int e = (int)(idx & (E_ - 1));
        int n = (int)(idx >> 12);
        int p = atomicAdd(&a.tcnt[e], 1);
        if (p < 2) { a.trows[e * 2 + p] = n; a.tvals[e * 2 + p] = v; }
    } else if (region == 1) {       // adjV: N x N
        int row = (int)(idx >> 11), col = (int)(idx & (N_ - 1));
        int s = atomicAdd(&a.avc[row], 1);
        if (s < CAP) { a.avj[row * CAP + s] = col; a.avv[row * CAP + s] = v; }
    } else {                        // adjE: E x E
        int row = (int)(idx >> 12), col = (int)(idx & (E_ - 1));
        int s = atomicAdd(&a.aec[row], 1);
        if (s < CAP) { a.aej[row * CAP + s] = col; a.aev[row * CAP + s] = v; }
    }
}

// ---- fused extraction + upconvert — EXACT round-0 structure (best measured:
// 43 us, VGPR=16, no spill). R3 coalesced-reg (49 us) and R4 LDS-DMA (49 us)
// variants proved the ~1.5 TB/s floor is invariant to access pattern; this
// phase is at its floor — do not re-attempt.
__global__ void k_extract_all(GArgs a, ConvArgs ca) {
    int b = blockIdx.x, t = threadIdx.x;
    int isbf = a.dt[1];
    if (b < 2048) {                 // T: N*E = 8.4M
        long long base = ((long long)b * 256 + t) * 16;
        float f[16];
        load8(a.T, base, isbf, f); load8(a.T, base + 8, isbf, f + 8);
#pragma unroll
        for (int k = 0; k < 16; k++)
            if (f[k] != 0.f) emit_one(a, 0, base + k, f[k]);
    } else if (b < 3072) {          // adjV: N*N = 4.2M
        long long base = ((long long)(b - 2048) * 256 + t) * 16;
        float f[16];
        load8(a.adjV, base, isbf, f); load8(a.adjV, base + 8, isbf, f + 8);
#pragma unroll
        for (int k = 0; k < 16; k++)
            if (f[k] != 0.f) emit_one(a, 1, base + k, f[k]);
    } else if (b < 7168) {          // adjE: E*E = 16.8M
        long long base = ((long long)(b - 3072) * 256 + t) * 16;
        float f[16];
        load8(a.adjE, base, isbf, f); load8(a.adjE, base + 8, isbf, f + 8);
#pragma unroll
        for (int k = 0; k < 16; k++)
            if (f[k] != 0.f) emit_one(a, 2, base + k, f[k]);
    } else {                        // upconvert inputs to f32
        int gb = b - 7168;
        int e = ca.blk_entry[gb];
        int off = (gb - ca.first[e]) * CHUNK;
        int n = ca.n[e];
        const void* src = ca.src[e];
        float* dst = ca.dst[e];
        int lim = min(off + CHUNK, n);
        for (int i = off + t * 8; i < lim; i += 256 * 8) {
            float f[8]; load8(src, i, isbf, f);
            float4* d = (float4*)(dst + i);
            d[0] = make_float4(f[0], f[1], f[2], f[3]);
            d[1] = make_float4(f[4], f[5], f[6], f[7]);
        }
    }
}

// ---- stage A: edge_map+gate1+scatter1 | edge_feat | fused W1 & Wf1 gemm+LN
__global__ void __launch_bounds__(128) k_stageA(GArgs a) {
    __shared__ float lds[256];
    __shared__ float red[8];
    int b = blockIdx.x, t = threadIdx.x;
    if (b < 32) {                   // per-edge: map + gate p1 + scatter into d1
        int e = b * 128 + t;
        if (a.tcnt[e] < 2) { a.eav[2 * e] = -1; a.eav[2 * e + 1] = -1; a.eprod[e] = 0.f; return; }
        int p = a.trows[2 * e], q = a.trows[2 * e + 1];
        int ia = -1, ib = -1;
        int np = min(a.avc[p], CAP), nq = min(a.avc[q], CAP);
        for (int s = 0; s < np; s++) if (a.avj[p * CAP + s] == q) { ia = p * CAP + s; break; }
        for (int s = 0; s < nq; s++) if (a.avj[q * CAP + s] == p) { ib = q * CAP + s; break; }
        float ep = a.tvals[2 * e] * a.tvals[2 * e + 1];
        a.eav[2 * e] = ia; a.eav[2 * e + 1] = ib; a.eprod[e] = ep;
        const float4* zr = (const float4*)(a.Zf + (long long)e * 16);
        const float4* pr = (const float4*)a.p1f;
        float s = 0.f;
#pragma unroll
        for (int qq = 0; qq < 4; qq++) {
            float4 h = zr[qq], pp = pr[qq];
            s += h.x * pp.x + h.y * pp.y + h.z * pp.z + h.w * pp.w;
        }
        float c = ep * s;
        if (ia >= 0) unsafeAtomicAdd(&a.d1[ia], a.avv[ia] * c);
        if (ib >= 0) unsafeAtomicAdd(&a.d1[ib], a.avv[ib] * c);
    } else if (b < 64) {            // edge_feat: HeW = relu(Z)@W2 ; F2 = relu(LN(Z@Wf2))
        int e = (b - 32) * 128 + t;
        const float4* zr = (const float4*)(a.Zf + (long long)e * 16);
        float zv[16];
        float4 z0 = zr[0], z1 = zr[1], z2 = zr[2], z3 = zr[3];
        zv[0] = z0.x; zv[1] = z0.y; zv[2] = z0.z; zv[3] = z0.w;
        zv[4] = z1.x; zv[5] = z1.y; zv[6] = z1.z; zv[7] = z1.w;
        zv[8] = z2.x; zv[9] = z2.y; zv[10] = z2.z; zv[11] = z2.w;
        zv[12] = z3.x; zv[13] = z3.y; zv[14] = z3.z; zv[15] = z3.w;
        float hw[16], f2[16];
#pragma unroll
        for (int c = 0; c < 16; c++) { hw[c] = 0.f; f2[c] = 0.f; }
#pragma unroll
        for (int k = 0; k < 16; k++) {
            float ar = fmaxf(zv[k], 0.f), az = zv[k];
#pragma unroll
            for (int c = 0; c < 16; c++) {
                hw[c] += ar * a.W2f[k * 16 + c];
                f2[c] += az * a.Wf2f[k * 16 + c];
            }
        }
        float m = 0.f;
#pragma unroll
        for (int c = 0; c < 16; c++) m += f2[c];
        m *= (1.f / 16.f);
        float var = 0.f;
#pragma unroll
        for (int c = 0; c < 16; c++) { float d = f2[c] - m; var += d * d; }
        var *= (1.f / 16.f);
        float rs = rsqrtf(var + 1e-5f);
#pragma unroll
        for (int c = 0; c < 16; c++)
            f2[c] = fmaxf((f2[c] - m) * rs * a.g2f[c] + a.be2f[c], 0.f);
        float4* ho = (float4*)(a.HeW + (long long)e * 16);
        ho[0] = make_float4(hw[0], hw[1], hw[2], hw[3]);
        ho[1] = make_float4(hw[4], hw[5], hw[6], hw[7]);
        ho[2] = make_float4(hw[8], hw[9], hw[10], hw[11]);
        ho[3] = make_float4(hw[12], hw[13], hw[14], hw[15]);
        float4* fo = (float4*)(a.F2 + (long long)e * 16);
        fo[0] = make_float4(f2[0], f2[1], f2[2], f2[3]);
        fo[1] = make_float4(f2[4], f2[5], f2[6], f2[7]);
        fo[2] = make_float4(f2[8], f2[9], f2[10], f2[11]);
        fo[3] = make_float4(f2[12], f2[13], f2[14], f2[15]);
    } else {                        // fused gemm W1 + gemmln Wf1, 4 rows/block
        int r0 = (b - 64) * 4;
        for (int j = t; j < 256; j += 128) lds[j] = a.Xf[(long long)r0 * 64 + j];
        __syncthreads();
        float h0 = 0.f, h1 = 0.f, h2 = 0.f, h3 = 0.f;
        float f0 = 0.f, f1 = 0.f, f2 = 0.f, f3 = 0.f;
#pragma unroll 8
        for (int k = 0; k < 64; k++) {
            float w1 = a.W1f[k * 128 + t], wf = a.Wf1f[k * 128 + t];
            float x0 = lds[k], x1 = lds[64 + k], x2 = lds[128 + k], x3 = lds[192 + k];
            h0 += x0 * w1; h1 += x1 * w1; h2 += x2 * w1; h3 += x3 * w1;
            f0 += x0 * wf; f1 += x1 * wf; f2 += x2 * wf; f3 += x3 * wf;
        }
        a.HW[(long long)(r0 + 0) * 128 + t] = h0;
        a.HW[(long long)(r0 + 1) * 128 + t] = h1;
        a.HW[(long long)(r0 + 2) * 128 + t] = h2;
        a.HW[(long long)(r0 + 3) * 128 + t] = h3;
        float s0 = f0, s1 = f1, s2 = f2, s3 = f3;
        for (int o = 32; o > 0; o >>= 1) {
            s0 += __shfl_down(s0, o); s1 += __shfl_down(s1, o);
            s2 += __shfl_down(s2, o); s3 += __shfl_down(s3, o);
        }
        if ((t & 63) == 0) {
            int w4 = (t >> 6) * 4;
            red[w4] = s0; red[w4 + 1] = s1; red[w4 + 2] = s2; red[w4 + 3] = s3;
        }
        __syncthreads();
        float m0 = (red[0] + red[4]) * (1.f / 128.f);
        float m1 = (red[1] + red[5]) * (1.f / 128.f);
        float m2 = (red[2] + red[6]) * (1.f / 128.f);
        float m3 = (red[3] + red[7]) * (1.f / 128.f);
        __syncthreads();
        float d0 = f0 - m0, d1 = f1 - m1, d2 = f2 - m2, d3 = f3 - m3;
        s0 = d0 * d0; s1 = d1 * d1; s2 = d2 * d2; s3 = d3 * d3;
        for (int o = 32; o > 0; o >>= 1) {
            s0 += __shfl_down(s0, o); s1 += __shfl_down(s1, o);
            s2 += __shfl_down(s2, o); s3 += __shfl_down(s3, o);
        }
        if ((t & 63) == 0) {
            int w4 = (t >> 6) * 4;
            red[w4] = s0; red[w4 + 1] = s1; red[w4 + 2] = s2; red[w4 + 3] = s3;
        }
        __syncthreads();
        float v0 = (red[0] + red[4]) * (1.f / 128.f);
        float v1 = (red[1] + red[5]) * (1.f / 128.f);
        float v2 = (red[2] + red[6]) * (1.f / 128.f);
        float v3 = (red[3] + red[7]) * (1.f / 128.f);
        float g = a.g1f[t], be = a.be1f[t];
        a.X1F1[(long long)(r0 + 0) * 256 + 128 + t] = fmaxf(d0 * rsqrtf(v0 + 1e-5f) * g + be, 0.f);
        a.X1F1[(long long)(r0 + 1) * 256 + 128 + t] = fmaxf(d1 * rsqrtf(v1 + 1e-5f) * g + be, 0.f);
        a.X1F1[(long long)(r0 + 2) * 256 + 128 + t] = fmaxf(d2 * rsqrtf(v2 + 1e-5f) * g + be, 0.f);
        a.X1F1[(long long)(r0 + 3) * 256 + 128 + t] = fmaxf(d3 * rsqrtf(v3 + 1e-5f) * g + be, 0.f);
    }
}

// node accumulate: 4-way unrolled neighbor loop (independent HW-row gathers
// raise MLP; named scalars only — register arrays spill, R2 lesson).
__device__ __forceinline__ float node_acc(const GArgs& a, int i, int c,
                                          const float* bia, const float* dd) {
    float acc = bia[c];
    int n = min(a.avc[i], CAP);
    int s = 0;
    for (; s + 4 <= n; s += 4) {
        int idx = i * CAP + s;
        int c0 = a.avj[idx], c1 = a.avj[idx + 1], c2 = a.avj[idx + 2], c3 = a.avj[idx + 3];
        float w0 = (c0 == i) ? a.avv[idx]     : dd[idx];
        float w1 = (c1 == i) ? a.avv[idx + 1] : dd[idx + 1];
        float w2 = (c2 == i) ? a.avv[idx + 2] : dd[idx + 2];
        float w3 = (c3 == i) ? a.avv[idx + 3] : dd[idx + 3];
        float h0 = a.HW[(long long)c0 * 128 + c];
        float h1 = a.HW[(long long)c1 * 128 + c];
        float h2 = a.HW[(long long)c2 * 128 + c];
        float h3 = a.HW[(long long)c3 * 128 + c];
        acc += w0 * h0 + w1 * h1 + w2 * h2 + w3 * h3;
    }
    for (; s < n; s++) {
        int idx = i * CAP + s;
        int col = a.avj[idx];
        float co = (col == i) ? a.avv[idx] : dd[idx];
        acc += co * a.HW[(long long)col * 128 + c];
    }
    return acc;
}

// ---- apply_node1 (delta form) + fused gate p2 -> s_n1
__global__ void __launch_bounds__(128) k_node1(GArgs a) {
    __shared__ float sm[2];
    int i = blockIdx.x, c = threadIdx.x;
    float acc = fmaxf(node_acc(a, i, c, a.b1f, a.d1), 0.f);
    a.X1F1[(long long)i * 256 + c] = acc;
    float f = a.X1F1[(long long)i * 256 + 128 + c];
    float v = acc * a.p2f[c] + f * a.p2f[128 + c];
    for (int o = 32; o > 0; o >>= 1) v += __shfl_down(v, o);
    if ((c & 63) == 0) sm[c >> 6] = v;
    __syncthreads();
    if (c == 0) a.s_n1[i] = sm[0] + sm[1];
}

__device__ __forceinline__ void adjA_slot(const GArgs& a, int k, const float* sn,
                                          float* aea, float* colmax) {
    int e = k >> 6, s = k & 63;
    if (s >= min(a.aec[e], CAP)) return;
    int f = a.aej[k];
    float M;
    if (e == f) {
        M = 1.f;
    } else {
        M = 0.f;
        int ce = min(a.tcnt[e], 2), cf = min(a.tcnt[f], 2);
        for (int x = 0; x < ce; x++) {
            int nx = a.trows[2 * e + x]; float ux = a.tvals[2 * e + x];
            for (int y = 0; y < cf; y++)
                if (a.trows[2 * f + y] == nx) M += ux * a.tvals[2 * f + y] * sn[nx];
        }
    }
    float v = M * a.aev[k];
    aea[k] = v;
    if (v > 0.f) atomicMax((int*)&colmax[f], __float_as_int(v));
}

// ---- stage C: adjA1 | gemm W3 (K=256, 4 rows/block)
__global__ void __launch_bounds__(128) k_stageC(GArgs a) {
    __shared__ float lds[1024];
    int b = blockIdx.x, t = threadIdx.x;
    if (b < 2048) {
        adjA_slot(a, b * 128 + t, a.s_n1, a.aea1, a.colmax1);
    } else {
        int r0 = (b - 2048) * 4;
        for (int j = t; j < 1024; j += 128) lds[j] = a.X1F1[(long long)r0 * 256 + j];
        __syncthreads();
        float a0 = 0.f, a1 = 0.f, a2 = 0.f, a3 = 0.f;
        for (int k = 0; k < 256; k++) {
            float w = a.W3f[k * 128 + t];
            a0 += lds[k] * w; a1 += lds[256 + k] * w;
            a2 += lds[512 + k] * w; a3 += lds[768 + k] * w;
        }
        a.HW[(long long)r0 * 128 + t] = a0;
        a.HW[(long long)(r0 + 1) * 128 + t] = a1;
        a.HW[(long long)(r0 + 2) * 128 + t] = a2;
        a.HW[(long long)(r0 + 3) * 128 + t] = a3;
    }
}

// ---- edge layer 1: wave-per-edge SpMM + gate p3 + scatter d2 + W4 rowmat
__global__ void __launch_bounds__(256) k_edge1(GArgs a) {
    int e = (blockIdx.x * 256 + threadIdx.x) >> 6;
    int ln = threadIdx.x & 63;
    int sub = ln >> 4, c = ln & 15;
    float acc = 0.f;
    int n = min(a.aec[e], CAP);
    for (int s = sub; s < n; s += 4) {
        int idx = e * CAP + s;
        int f = a.aej[idx];
        float cm = a.colmax1[f];
        float nv = (cm != 0.f) ? a.aea1[idx] / cm : 0.f;
        acc += nv * a.HeW[(long long)f * 16 + c];
    }
    acc += __shfl_xor(acc, 16);
    acc += __shfl_xor(acc, 32);
    float tot = fmaxf(a.b2f[c] + acc, 0.f);         // Z2[e,c]
    float f2 = a.F2[(long long)e * 16 + c];
    float v = tot * a.p3f[c] + f2 * a.p3f[16 + c];
#pragma unroll
    for (int m = 1; m < 16; m <<= 1) v += __shfl_xor(v, m);
    if (ln == 0) {
        float ep = a.eprod[e];
        if (ep != 0.f) {
            float cc = ep * v;
            int i1 = a.eav[2 * e], i2 = a.eav[2 * e + 1];
            if (i1 >= 0) unsafeAtomicAdd(&a.d2[i1], a.avv[i1] * cc);
            if (i2 >= 0) unsafeAtomicAdd(&a.d2[i2], a.avv[i2] * cc);
        }
    }
    float o = 0.f;
#pragma unroll
    for (int k = 0; k < 16; k++) {
        o += __shfl(tot, k, 16) * a.W4f[k * 16 + c];
        o += __shfl(f2, k, 16) * a.W4f[(16 + k) * 16 + c];
    }
    if (ln < 16) a.HeW2[(long long)e * 16 + c] = o;
}

// ---- apply_node3 + fused gate p4 -> s_n2
__global__ void __launch_bounds__(128) k_node3(GArgs a) {
    __shared__ float sm[2];
    int i = blockIdx.x, c = threadIdx.x;
    float acc = fmaxf(node_acc(a, i, c, a.b3f, a.d2), 0.f);
    a.X3[(long long)i * 128 + c] = acc;
    float v = acc * a.p4f[c];
    for (int o = 32; o > 0; o >>= 1) v += __shfl_down(v, o);
    if ((c & 63) == 0) sm[c >> 6] = v;
    __syncthreads();
    if (c == 0) a.s_n2[i] = sm[0] + sm[1];
}

// ---- stage F: adjA2 | gemm W5 (K=128, 4 rows/block)
__global__ void __launch_bounds__(128) k_stageF(GArgs a) {
    __shared__ float lds[512];
    int b = blockIdx.x, t = threadIdx.x;
    if (b < 2048) {
        adjA_slot(a, b * 128 + t, a.s_n2, a.aea2, a.colmax2);
    } else {
        int r0 = (b - 2048) * 4;
        for (int j = t; j < 512; j += 128) lds[j] = a.X3[(long long)r0 * 128 + j];
        __syncthreads();
        float a0 = 0.f, a1 = 0.f, a2 = 0.f, a3 = 0.f;
        for (int k = 0; k < 128; k++) {
            float w = a.W5f[k * 128 + t];
            a0 += lds[k] * w; a1 += lds[128 + k] * w;
            a2 += lds[256 + k] * w; a3 += lds[384 + k] * w;
        }
        a.HW[(long long)r0 * 128 + t] = a0;
        a.HW[(long long)(r0 + 1) * 128 + t] = a1;
        a.HW[(long long)(r0 + 2) * 128 + t] = a2;
        a.HW[(long long)(r0 + 3) * 128 + t] = a3;
    }
}

// ---- edge layer 2: wave-per-edge SpMM + gate p5 + scatter d3
__global__ void __launch_bounds__(256) k_edge2(GArgs a) {
    int e = (blockIdx.x * 256 + threadIdx.x) >> 6;
    int ln = threadIdx.x & 63;
    int sub = ln >> 4, c = ln & 15;
    float acc = 0.f;
    int n = min(a.aec[e], CAP);
    for (int s = sub; s < n; s += 4) {
        int idx = e * CAP + s;
        int f = a.aej[idx];
        float cm = a.colmax2[f];
        float nv = (cm != 0.f) ? a.aea2[idx] / cm : 0.f;
        acc += nv * a.HeW2[(long long)f * 16 + c];
    }
    acc += __shfl_xor(acc, 16);
    acc += __shfl_xor(acc, 32);
    float tot = fmaxf(a.b4f[c] + acc, 0.f);         // Z4[e,c]
    float v = tot * a.p5f[c];
#pragma unroll
    for (int m = 1; m < 16; m <<= 1) v += __shfl_xor(v, m);
    if (ln == 0) {
        float ep = a.eprod[e];
        if (ep != 0.f) {
            float cc = ep * v;
            int i1 = a.eav[2 * e], i2 = a.eav[2 * e + 1];
            if (i1 >= 0) unsafeAtomicAdd(&a.d3[i1], a.avv[i1] * cc);
            if (i2 >= 0) unsafeAtomicAdd(&a.d3[i2], a.avv[i2] * cc);
        }
    }
}

// ---- apply_node5 -> d_out
__global__ void __launch_bounds__(128) k_node5(GArgs a) {
    int i = blockIdx.x, c = threadIdx.x;
    float acc = node_acc(a, i, c, a.b5f, a.d3);
    if (a.dt[1]) ((bf16*)a.out)[(long long)i * 128 + c] = __float2bfloat16(acc);
    else         ((float*)a.out)[(long long)i * 128 + c] = acc;
}

extern "C" void kernel_launch(void* const* d_in, const int* in_sizes, int n_in,
                              void* d_out, int out_size, void* d_ws, size_t ws_size,
                              hipStream_t stream) {
    char* wsB = (char*)d_ws;
    size_t off = 0;
    auto alloc = [&](size_t bytes) -> void* {
        void* p = wsB + off;
        off += (bytes + 255) & ~(size_t)255;
        return p;
    };
    // --- contiguous zero-init block (zeroed by k_init) ---
    int*   dt      = (int*)alloc(2 * 4);
    int*   tcnt    = (int*)alloc(E_ * 4);
    int*   avc     = (int*)alloc(N_ * 4);
    int*   aec     = (int*)alloc(E_ * 4);
    float* colmax1 = (float*)alloc(E_ * 4);
    float* colmax2 = (float*)alloc(E_ * 4);
    float* d1      = (float*)alloc((size_t)N_ * CAP * 4);
    float* d2      = (float*)alloc((size_t)N_ * CAP * 4);
    float* d3      = (float*)alloc((size_t)N_ * CAP * 4);
    size_t zero_bytes = off;
    // --- converted f32 inputs ---
    float* Xf  = (float*)alloc((size_t)N_ * 64 * 4);
    float* Zf  = (float*)alloc((size_t)E_ * 16 * 4);
    float* W1f = (float*)alloc(8192 * 4);  float* p1f = (float*)alloc(16 * 4);
    float* b1f = (float*)alloc(128 * 4);
    float* Wf1f = (float*)alloc(8192 * 4); float* g1f = (float*)alloc(128 * 4);
    float* be1f = (float*)alloc(128 * 4);
    float* W2f = (float*)alloc(256 * 4);   float* p2f = (float*)alloc(256 * 4);
    float* b2f = (float*)alloc(16 * 4);
    float* Wf2f = (float*)alloc(256 * 4);  float* g2f = (float*)alloc(16 * 4);
    float* be2f = (float*)alloc(16 * 4);
    float* W3f = (float*)alloc(32768 * 4); float* p3f = (float*)alloc(32 * 4);
    float* b3f = (float*)alloc(128 * 4);
    float* W4f = (float*)alloc(512 * 4);   float* p4f = (float*)alloc(128 * 4);
    float* b4f = (float*)alloc(16 * 4);
    float* W5f = (float*)alloc(16384 * 4); float* p5f = (float*)alloc(16 * 4);
    float* b5f = (float*)alloc(128 * 4);
    // --- sparse structures + activations ---
    int*   trows  = (int*)alloc(E_ * 2 * 4);
    float* tvals  = (float*)alloc(E_ * 2 * 4);
    int*   avj    = (int*)alloc((size_t)N_ * CAP * 4);
    float* avv    = (float*)alloc((size_t)N_ * CAP * 4);
    int*   aej    = (int*)alloc((size_t)E_ * CAP * 4);
    float* aev    = (float*)alloc((size_t)E_ * CAP * 4);
    float* aea1   = (float*)alloc((size_t)E_ * CAP * 4);
    float* aea2   = (float*)alloc((size_t)E_ * CAP * 4);
    int*   eav    = (int*)alloc(E_ * 2 * 4);
    float* eprod  = (float*)alloc(E_ * 4);
    float* s_n1   = (float*)alloc(N_ * 4);
    float* s_n2   = (float*)alloc(N_ * 4);
    float* X1F1   = (float*)alloc((size_t)N_ * 256 * 4);
    float* F2b    = (float*)alloc((size_t)E_ * 16 * 4);
    float* HW     = (float*)alloc((size_t)N_ * 128 * 4);
    float* HeW    = (float*)alloc((size_t)E_ * 16 * 4);
    float* HeW2   = (float*)alloc((size_t)E_ * 16 * 4);
    float* X3     = (float*)alloc((size_t)N_ * 128 * 4);

    ConvArgs ca{};
    int ne = 0;
    auto addc = [&](const void* s, float* d, int n) {
        ca.src[ne] = s; ca.dst[ne] = d; ca.n[ne] = n; ne++;
    };
    addc(d_in[0], Xf, N_ * 64);  addc(d_in[1], Zf, E_ * 16);
    addc(d_in[5], W1f, 8192);   addc(d_in[6], p1f, 16);   addc(d_in[7], b1f, 128);
    addc(d_in[8], Wf1f, 8192);  addc(d_in[9], g1f, 128);  addc(d_in[10], be1f, 128);
    addc(d_in[11], W2f, 256);   addc(d_in[12], p2f, 256); addc(d_in[13], b2f, 16);
    addc(d_in[14], Wf2f, 256);  addc(d_in[15], g2f, 16);  addc(d_in[16], be2f, 16);
    addc(d_in[17], W3f, 32768); addc(d_in[18], p3f, 32);  addc(d_in[19], b3f, 128);
    addc(d_in[20], W4f, 512);   addc(d_in[21], p4f, 128); addc(d_in[22], b4f, 16);
    addc(d_in[23], W5f, 16384); addc(d_in[24], p5f, 16);  addc(d_in[25], b5f, 128);
    int nb = 0;
    for (int e = 0; e < ne; e++) {
        ca.first[e] = nb;
        int k = (ca.n[e] + CHUNK - 1) / CHUNK;
        for (int j = 0; j < k; j++) ca.blk_entry[nb++] = (unsigned char)e;
    }

    GArgs a{d_in[4], d_in[3], d_in[2], dt,
            tcnt, trows, tvals, avc, avj, avv, aec, aej, aev,
            eav, eprod, d1, d2, d3, aea1, aea2, colmax1, colmax2,
            s_n1, s_n2, Xf, Zf,
            W1f, p1f, b1f, Wf1f, g1f, be1f,
            W2f, p2f, b2f, Wf2f, g2f, be2f,
            W3f, p3f, b3f, W4f, p4f, b4f,
            W5f, p5f, b5f,
            X1F1, F2b, HW, HeW, HeW2, X3, d_out,
            (int)(zero_bytes / 16)};

    // 10 dispatches (was 11: memset+detect fused into k_init)
    k_init<<<1024, 256, 0, stream>>>(a);
    k_extract_all<<<7168 + nb, 256, 0, stream>>>(a, ca);
    k_stageA<<<576, 128, 0, stream>>>(a);
    k_node1<<<N_, 128, 0, stream>>>(a);
    k_stageC<<<2560, 128, 0, stream>>>(a);
    k_edge1<<<E_ / 4, 256, 0, stream>>>(a);
    k_node3<<<N_, 128, 0, stream>>>(a);
    k_stageF<<<2560, 128, 0, stream>>>(a);
    k_edge2<<<E_ / 4, 256, 0, stream>>>(a);
    k_node5<<<N_, 128, 0, stream>>>(a);
}